// Round 4
// baseline (421.502 us; speedup 1.0000x reference)
//
#include <hip/hip_runtime.h>

#define S 2048
#define HID 2048
#define NH 16
#define DH 128
#define VOC 128
#define K2EXP 0.12752551286084112f   // (1/sqrt(128)) * log2(e)
#define RTHR 62.0f                   // defer-max threshold in raw-score units (~8 in exp2 units)
#define NEGS -3.0e38f

typedef __bf16 bf16_t;
typedef __attribute__((ext_vector_type(8))) __bf16 bf16x8;
typedef __attribute__((ext_vector_type(4))) __bf16 bf16x4;
typedef __attribute__((ext_vector_type(4))) float f32x4;
typedef __attribute__((ext_vector_type(16))) float f32x16;

typedef __attribute__((address_space(1))) unsigned int guint;
typedef __attribute__((address_space(3))) unsigned int luint;

#define MFMA16 __builtin_amdgcn_mfma_f32_16x16x32_bf16
#define MFMA32 __builtin_amdgcn_mfma_f32_32x32x16_bf16

__device__ __forceinline__ void gl_lds16(const void* g, void* l) {
  __builtin_amdgcn_global_load_lds((guint*)(unsigned long long)g,
                                   (luint*)(unsigned)(unsigned long long)l,
                                   16, 0, 0);
}

__device__ __forceinline__ unsigned cvtpk(float lo, float hi) {
  unsigned r;
  asm("v_cvt_pk_bf16_f32 %0, %1, %2" : "=v"(r) : "v"(lo), "v"(hi));
  return r;
}
__device__ __forceinline__ void plswap(unsigned& a, unsigned& b) {
  asm volatile("v_permlane32_swap_b32 %0, %1" : "+v"(a), "+v"(b));
}
__device__ __forceinline__ bf16x8 mk8(unsigned d0, unsigned d1, unsigned d2, unsigned d3) {
  union { unsigned u[4]; bf16x8 v; } x;
  x.u[0] = d0; x.u[1] = d1; x.u[2] = d2; x.u[3] = d3;
  return x.v;
}

// ---------------- mask interval precompute ----------------
__global__ __launch_bounds__(256) void mask_prep(const int* __restrict__ tokens,
                                                 const unsigned char* __restrict__ seg,
                                                 const unsigned char* __restrict__ spc,
                                                 int4* __restrict__ mi) {
  __shared__ int ssp[257], ssg[257];
  __shared__ int slay;
  int t = threadIdx.x;
  if (t == 0) {
    int nz = 0, f32c = 0;
    for (int i = 0; i < 256; i++) {
      if ((i & 3) != 0 && seg[i]) nz++;
      if ((i & 3) == 3 && seg[i] == 0x3f) f32c++;
    }
    slay = (f32c > 8) ? 2 : ((nz > 4) ? 1 : 0);
  }
  __syncthreads();
  int lay = slay;
  auto getb = [&](const unsigned char* p, int i) -> int {
    if (lay == 1) return p[i] != 0;
    if (lay == 2) return ((const float*)p)[i] != 0.f;
    return ((const int*)p)[i] != 0;
  };
  int base = t * 8, a = 0, b = 0;
  for (int j = 0; j < 8; j++) { a += getb(spc, base + j); b += 1 - getb(seg, base + j); }
  ssp[t + 1] = a; ssg[t + 1] = b;
  __syncthreads();
  if (t == 0) {
    ssp[0] = 0; ssg[0] = 0;
    for (int i = 1; i <= 256; i++) { ssp[i] += ssp[i - 1]; ssg[i] += ssg[i - 1]; }
  }
  __syncthreads();
  int esp = ssp[t], esg = ssg[t];
  for (int j = 0; j < 8; j++) {
    int i = base + j;
    int sp = getb(spc, i), sg = 1 - getb(seg, i);
    int np = (tokens[i] != 127) ? 1 : 0;
    int wint = (i == 0) ? (1 + sp) : (1 + esp);
    int sint = (i == 0) ? (1 + sg) : (1 + esg);
    mi[i] = make_int4(np | (sp << 1) | (sg << 2), wint, sint, 0);
    esp += sp; esg += sg;
  }
}

// ---------------- full mask bit table: cmask[word][q], word=kv/32 ----------------
__global__ __launch_bounds__(256) void bitgen(const int4* __restrict__ mi,
                                              unsigned* __restrict__ cmask) {
  __shared__ int4 km[32];
  int w = blockIdx.x;
  int t = threadIdx.x;
  int q = blockIdx.y * 256 + t;
  if (t < 32) km[t] = mi[w * 32 + t];
  __syncthreads();
  int4 mq = mi[q];
  unsigned word = 0;
  #pragma unroll
  for (int j = 0; j < 32; j++) {
    int kv = w * 32 + j;
    int4 mk = km[j];
    bool v = ((mq.x & mk.x) & 1) &&
             ((mk.x & 2) || (mq.y == mk.y)) &&
             ((mk.x & 4) || (mq.z == mk.z)) &&
             (kv <= q);
    word |= (v ? 1u : 0u) << j;
  }
  cmask[(size_t)w * S + q] = word;
}

// ---------------- shared transpose-store helper (embed) ----------------
__device__ __forceinline__ void store_h_hT(bf16x8 ob[4], bf16_t* tile, int q0, int h,
                                           int ql, int d0, int tid,
                                           bf16_t* __restrict__ hb, bf16_t* __restrict__ hbT) {
  #pragma unroll
  for (int i = 0; i < 4; i++)
    *(bf16x8*)(hb + (size_t)(q0 + ql) * HID + h * DH + d0 + i * 8) = ob[i];
  #pragma unroll
  for (int i = 0; i < 4; i++)
    #pragma unroll
    for (int j = 0; j < 8; j++) tile[ql * 136 + d0 + i * 8 + j] = ob[i][j];
  __syncthreads();
  int dT = tid >> 1, qh = (tid & 1) * 32;
  bf16x8 tb[4];
  #pragma unroll
  for (int i = 0; i < 4; i++)
    #pragma unroll
    for (int j = 0; j < 8; j++) tb[i][j] = tile[(qh + i * 8 + j) * 136 + dT];
  #pragma unroll
  for (int i = 0; i < 4; i++)
    *(bf16x8*)(hbT + (size_t)(h * DH + dT) * S + q0 + qh + i * 8) = tb[i];
}

// ---------------- embedding gather -> bf16 h and h^T ----------------
__global__ __launch_bounds__(256) void embedT(const int* __restrict__ tokens,
                                              const float* __restrict__ emb,
                                              bf16_t* __restrict__ hb, bf16_t* __restrict__ hbT) {
  __shared__ bf16_t tile[64 * 136];
  int tid = threadIdx.x;
  int q0 = blockIdx.x * 64, h = blockIdx.y;
  int ql = tid >> 2, d0 = (tid & 3) * 32;
  int tok = tokens[q0 + ql];
  const float4* src = (const float4*)(emb + (size_t)tok * HID + h * DH + d0);
  bf16x8 ob[4];
  #pragma unroll
  for (int i = 0; i < 8; i++) {
    float4 f = src[i];
    ob[i >> 1][(i & 1) * 4 + 0] = (bf16_t)f.x;
    ob[i >> 1][(i & 1) * 4 + 1] = (bf16_t)f.y;
    ob[i >> 1][(i & 1) * 4 + 2] = (bf16_t)f.z;
    ob[i >> 1][(i & 1) * 4 + 3] = (bf16_t)f.w;
  }
  store_h_hT(ob, tile, q0, h, ql, d0, tid, hb, hbT);
}

// ---------------- fused attention layer (32x32 MFMA, in-reg softmax) ----------------
__global__ __launch_bounds__(256, 1) void attn2(const bf16_t* __restrict__ hb,
                                                const bf16_t* __restrict__ hbT,
                                                const unsigned* __restrict__ cmask,
                                                bf16_t* __restrict__ ob,
                                                bf16_t* __restrict__ obT,
                                                int writeT) {
  __shared__ __align__(16) char lds_raw[65536];

  int h = blockIdx.x, qg = blockIdx.y;
  int tid = threadIdx.x, w = tid >> 6, l = tid & 63, l31 = l & 31, hi = l >> 5;
  int tile = qg + 16 * w, q0 = tile * 32, q = q0 + l31;

  // Q fragments (B operand): lane holds Q[q=l31][d = 16ks + 8hi + j]
  bf16x8 qf[8];
  {
    const bf16_t* hq = hb + (size_t)q * HID + h * DH;
    #pragma unroll
    for (int ks = 0; ks < 8; ks++) qf[ks] = *(const bf16x8*)(hq + ks * 16 + hi * 8);
  }

  f32x16 acc[4];
  #pragma unroll
  for (int i = 0; i < 4; i++)
    #pragma unroll
    for (int r = 0; r < 16; r++) acc[i][r] = 0.f;
  float m = -1e30f, lsum = 0.f;

  int myTi = (tile * 32 + 31) >> 6;
  int nT = (((qg + 48) * 32 + 31) >> 6) + 1;
  int swz = l31 & 7;

  auto STAGE = [&](int t, int b) {
    int kv0 = t * 64;
    bf16_t* Kb = (bf16_t*)(lds_raw + b * 16384);
    bf16_t* Vb = (bf16_t*)(lds_raw + 32768 + b * 16384);
    #pragma unroll
    for (int i = 0; i < 4; i++) {
      int seg = w * 4 + i;
      int row = seg * 4 + (l >> 4);
      int ch = (l & 15) ^ (row & 7);
      gl_lds16(hb + (size_t)(kv0 + row) * HID + h * DH + ch * 8, Kb + seg * 512);
    }
    #pragma unroll
    for (int i = 0; i < 4; i++) {
      int seg = w * 4 + i;
      int row = seg * 8 + (l >> 3);
      int ch = (l & 7) ^ (row & 7);
      gl_lds16(hbT + (size_t)(h * DH + row) * S + kv0 + ch * 8, Vb + seg * 512);
    }
  };

  STAGE(0, 0);
  for (int t = 0; t < nT; t++) {
    int b = t & 1;
    if (t + 1 < nT) {
      STAGE(t + 1, b ^ 1);
      asm volatile("s_waitcnt vmcnt(8)" ::: "memory");
    } else {
      asm volatile("s_waitcnt vmcnt(0)" ::: "memory");
    }
    __builtin_amdgcn_s_barrier();
    __builtin_amdgcn_sched_barrier(0);

    if (t <= myTi) {
      const bf16_t* Kb = (const bf16_t*)(lds_raw + b * 16384);
      const bf16_t* Vb = (const bf16_t*)(lds_raw + 32768 + b * 16384);
      // QK^T swapped: D[kv][q], two 32-kv blocks
      f32x16 s0, s1;
      #pragma unroll
      for (int r = 0; r < 16; r++) { s0[r] = 0.f; s1[r] = 0.f; }
      const bf16_t* k0p = Kb + l31 * 128;
      const bf16_t* k1p = Kb + (32 + l31) * 128;
      #pragma unroll
      for (int ks = 0; ks < 8; ks++) {
        int ch = ((2 * ks + hi) ^ swz) * 8;
        bf16x8 kf0 = *(const bf16x8*)(k0p + ch);
        bf16x8 kf1 = *(const bf16x8*)(k1p + ch);
        s0 = MFMA32(kf0, qf[ks], s0, 0, 0, 0);
        s1 = MFMA32(kf1, qf[ks], s1, 0, 0, 0);
      }

      unsigned w0 = cmask[(size_t)(2 * t) * S + q];
      unsigned w1 = cmask[(size_t)(2 * t + 1) * S + q];
      float sv0[16], sv1[16];
      float mx = NEGS;
      #pragma unroll
      for (int r = 0; r < 16; r++) {
        int bit = (r & 3) + 8 * (r >> 2) + 4 * hi;
        sv0[r] = ((w0 >> bit) & 1u) ? s0[r] : NEGS;
        sv1[r] = ((w1 >> bit) & 1u) ? s1[r] : NEGS;
        mx = fmaxf(mx, fmaxf(sv0[r], sv1[r]));
      }
      mx = fmaxf(mx, __shfl_xor(mx, 32, 64));
      if (__any(mx > m + RTHR)) {
        float mn = fmaxf(m, mx);
        float al = exp2f((m - mn) * K2EXP);
        m = mn; lsum *= al;
        #pragma unroll
        for (int r = 0; r < 16; r++) {
          float alr = __shfl(al, (r & 3) + 8 * (r >> 2) + 4 * hi, 64);
          #pragma unroll
          for (int d = 0; d < 4; d++) acc[d][r] *= alr;
        }
      }
      float mk = m * K2EXP;
      float p0[16], p1[16], ps = 0.f;
      #pragma unroll
      for (int r = 0; r < 16; r++) {
        p0[r] = exp2f(__builtin_fmaf(sv0[r], K2EXP, -mk));
        p1[r] = exp2f(__builtin_fmaf(sv1[r], K2EXP, -mk));
        ps += p0[r] + p1[r];
      }
      ps += __shfl_xor(ps, 32, 64);
      lsum += ps;

      // pack P -> A-fragments via cvt_pk + permlane32_swap (T12)
      bf16x8 pa[4];
      {
        unsigned a0 = cvtpk(p0[0], p0[1]),  a1 = cvtpk(p0[2], p0[3]);
        unsigned b0 = cvtpk(p0[4], p0[5]),  b1 = cvtpk(p0[6], p0[7]);
        unsigned a2 = cvtpk(p0[8], p0[9]),  a3 = cvtpk(p0[10], p0[11]);
        unsigned b2 = cvtpk(p0[12], p0[13]), b3 = cvtpk(p0[14], p0[15]);
        plswap(a0, b0); plswap(a1, b1); plswap(a2, b2); plswap(a3, b3);
        pa[0] = mk8(a0, a1, b0, b1);
        pa[1] = mk8(a2, a3, b2, b3);
        unsigned c0 = cvtpk(p1[0], p1[1]),  c1 = cvtpk(p1[2], p1[3]);
        unsigned d0 = cvtpk(p1[4], p1[5]),  d1 = cvtpk(p1[6], p1[7]);
        unsigned c2 = cvtpk(p1[8], p1[9]),  c3 = cvtpk(p1[10], p1[11]);
        unsigned d2 = cvtpk(p1[12], p1[13]), d3 = cvtpk(p1[14], p1[15]);
        plswap(c0, d0); plswap(c1, d1); plswap(c2, d2); plswap(c3, d3);
        pa[2] = mk8(c0, c1, d0, d1);
        pa[3] = mk8(c2, c3, d2, d3);
      }

      // PV: O[q][d] += P V, 4 d-blocks of 32
      #pragma unroll
      for (int db = 0; db < 4; db++) {
        const bf16_t* vr = Vb + (32 * db + l31) * 64;
        #pragma unroll
        for (int ks = 0; ks < 4; ks++) {
          bf16x8 vf = *(const bf16x8*)(vr + ((2 * ks + hi) ^ swz) * 8);
          acc[db] = MFMA32(pa[ks], vf, acc[db], 0, 0, 0);
        }
      }
    }
    __builtin_amdgcn_s_barrier();
  }

  // epilogue: normalize, write hb and hbT (reuse LDS)
  __syncthreads();
  bf16_t* tl = (bf16_t*)lds_raw + w * (32 * 132);
  float inv = (lsum > 0.f) ? 1.f / lsum : 0.f;   // per-lane q = l31
  #pragma unroll
  for (int r = 0; r < 16; r++) {
    int qr = (r & 3) + 8 * (r >> 2) + 4 * hi;
    float ivr = __shfl(inv, qr, 64);
    #pragma unroll
    for (int db = 0; db < 4; db++)
      tl[qr * 132 + db * 32 + l31] = (bf16_t)(acc[db][r] * ivr);
  }
  asm volatile("s_waitcnt lgkmcnt(0)" ::: "memory");
  __builtin_amdgcn_sched_barrier(0);
  {
    int qr2 = l >> 1;
    #pragma unroll
    for (int k = 0; k < 8; k++) {
      int ch = (l & 1) * 8 + k;
      bf16x8 v = *(const bf16x8*)(tl + qr2 * 132 + ch * 8);
      *(bf16x8*)(ob + (size_t)(q0 + qr2) * HID + h * DH + ch * 8) = v;
    }
  }
  if (writeT) {
    #pragma unroll
    for (int j = 0; j < 2; j++) {
      int dd = l + 64 * j;
      #pragma unroll
      for (int c = 0; c < 4; c++) {
        bf16x8 v;
        #pragma unroll
        for (int k = 0; k < 8; k++) v[k] = tl[(c * 8 + k) * 132 + dd];
        *(bf16x8*)(obT + (size_t)(h * DH + dd) * S + q0 + c * 8) = v;
      }
    }
  }
}

// ---------------- lm head ----------------
__global__ __launch_bounds__(256) void wcvt(const float* __restrict__ w, bf16_t* __restrict__ wb) {
  int i = blockIdx.x * 256 + threadIdx.x;
  float4 f = ((const float4*)w)[i];
  bf16x4 v;
  v[0] = (bf16_t)f.x; v[1] = (bf16_t)f.y; v[2] = (bf16_t)f.z; v[3] = (bf16_t)f.w;
  *(bf16x4*)(wb + (size_t)i * 4) = v;
}

__global__ __launch_bounds__(256) void lm_head(const bf16_t* __restrict__ hb,
                                               const bf16_t* __restrict__ wbf,
                                               const float* __restrict__ bias,
                                               float* __restrict__ out) {
  __shared__ float red[4][16][130];
  int tid = threadIdx.x;
  int w = tid >> 6, l = tid & 63, l16 = l & 15, g = l >> 4;
  int t0 = blockIdx.x * 16;
  f32x4 acc[8];
  #pragma unroll
  for (int i = 0; i < 8; i++) acc[i] = (f32x4){0.f, 0.f, 0.f, 0.f};
  const bf16_t* arow = hb + (size_t)(t0 + l16) * HID + w * 512;
  for (int k0 = 0; k0 < 512; k0 += 32) {
    bf16x8 af = *(const bf16x8*)(arow + k0 + g * 8);
    #pragma unroll
    for (int vt = 0; vt < 8; vt++) {
      bf16x8 bf_ = *(const bf16x8*)(wbf + (size_t)(vt * 16 + l16) * HID + w * 512 + k0 + g * 8);
      acc[vt] = MFMA16(af, bf_, acc[vt], 0, 0, 0);
    }
  }
  #pragma unroll
  for (int vt = 0; vt < 8; vt++)
    #pragma unroll
    for (int r = 0; r < 4; r++)
      red[w][4 * g + r][vt * 16 + l16] = acc[vt][r];
  __syncthreads();
  int q = tid >> 4, vc = (tid & 15) * 8;
  #pragma unroll
  for (int j = 0; j < 8; j++) {
    float s = red[0][q][vc + j] + red[1][q][vc + j] + red[2][q][vc + j] + red[3][q][vc + j];
    out[(size_t)(t0 + q) * VOC + vc + j] = s + bias[vc + j];
  }
}

// ---------------- segment head (bf16 hidden) ----------------
__global__ __launch_bounds__(256) void seg_head(const bf16_t* __restrict__ hb,
                                                const float* __restrict__ sw,
                                                const float* __restrict__ sb,
                                                float* __restrict__ out) {
  int tid = threadIdx.x;
  int token = blockIdx.x * 8 + (tid >> 5);
  int lane = tid & 31;
  const bf16x8* hr = (const bf16x8*)(hb + (size_t)token * HID);
  const float4* w0 = (const float4*)sw;
  const float4* w1 = (const float4*)(sw + HID);
  float a0 = 0.f, a1 = 0.f;
  #pragma unroll
  for (int i = 0; i < 8; i++) {
    int c = lane + i * 32;
    bf16x8 v = hr[c];
    float4 x0 = w0[c * 2], x1 = w0[c * 2 + 1];
    float4 y0 = w1[c * 2], y1 = w1[c * 2 + 1];
    a0 += (float)v[0]*x0.x + (float)v[1]*x0.y + (float)v[2]*x0.z + (float)v[3]*x0.w
        + (float)v[4]*x1.x + (float)v[5]*x1.y + (float)v[6]*x1.z + (float)v[7]*x1.w;
    a1 += (float)v[0]*y0.x + (float)v[1]*y0.y + (float)v[2]*y0.z + (float)v[3]*y0.w
        + (float)v[4]*y1.x + (float)v[5]*y1.y + (float)v[6]*y1.z + (float)v[7]*y1.w;
  }
  #pragma unroll
  for (int off = 16; off; off >>= 1) {
    a0 += __shfl_xor(a0, off, 64);
    a1 += __shfl_xor(a1, off, 64);
  }
  if (lane == 0) {
    out[(size_t)token * 2] = a0 + sb[0];
    out[(size_t)token * 2 + 1] = a1 + sb[1];
  }
}

extern "C" void kernel_launch(void* const* d_in, const int* in_sizes, int n_in,
                              void* d_out, int out_size, void* d_ws, size_t ws_size,
                              hipStream_t stream) {
  const int* tokens = (const int*)d_in[0];
  const unsigned char* seg = (const unsigned char*)d_in[1];
  const unsigned char* spc = (const unsigned char*)d_in[2];
  const float* emb_w = (const float*)d_in[3];
  const float* lm_w = (const float*)d_in[4];
  const float* lm_b = (const float*)d_in[5];
  const float* seg_w = (const float*)d_in[6];
  const float* seg_b = (const float*)d_in[7];

  char* ws = (char*)d_ws;
  int4* mi = (int4*)ws;                                  // 32KB @0
  unsigned* cmask = (unsigned*)(ws + (64u << 10));       // 512KB @64KB
  bf16_t* hbA  = (bf16_t*)(ws + (1u << 20));             // 8MB @1MB
  bf16_t* hbTA = (bf16_t*)(ws + (9u << 20));             // 8MB @9MB
  bf16_t* hbB  = (bf16_t*)(ws + (17u << 20));            // 8MB @17MB
  bf16_t* hbTB = (bf16_t*)(ws + (25u << 20));            // 8MB @25MB
  bf16_t* wbf  = (bf16_t*)(ws + (33u << 20));            // 512KB @33MB
  float* out = (float*)d_out;

  mask_prep<<<1, 256, 0, stream>>>(tokens, seg, spc, mi);
  bitgen<<<dim3(64, 8), 256, 0, stream>>>(mi, cmask);
  embedT<<<dim3(S / 64, NH), 256, 0, stream>>>(tokens, emb_w, hbA, hbTA);

  bf16_t* cur = hbA;  bf16_t* curT = hbTA;
  bf16_t* nxt = hbB;  bf16_t* nxtT = hbTB;
  for (int L = 0; L < 4; L++) {
    attn2<<<dim3(NH, 16), 256, 0, stream>>>(cur, curT, cmask, nxt, nxtT, (L < 3) ? 1 : 0);
    bf16_t* t1 = cur; cur = nxt; nxt = t1;
    bf16_t* t2 = curT; curT = nxtT; nxtT = t2;
  }

  wcvt<<<(VOC * HID / 4) / 256, 256, 0, stream>>>(lm_w, wbf);
  lm_head<<<S / 16, 256, 0, stream>>>(cur, wbf, lm_b, out);
  seg_head<<<S / 8, 256, 0, stream>>>(cur, seg_w, seg_b, out + (size_t)S * VOC);
}

// Round 5
// 340.634 us; speedup vs baseline: 1.2374x; 1.2374x over previous
//
#include <hip/hip_runtime.h>

#define S 2048
#define HID 2048
#define NH 16
#define DH 128
#define VOC 128
#define K2EXP 0.12752551286084112f   // (1/sqrt(128)) * log2(e)
#define RTHR 62.0f                   // defer-max threshold in raw-score units (~8 in exp2 units)
#define NEGS -3.0e38f

typedef __bf16 bf16_t;
typedef __attribute__((ext_vector_type(8))) __bf16 bf16x8;
typedef __attribute__((ext_vector_type(4))) __bf16 bf16x4;
typedef __attribute__((ext_vector_type(4))) float f32x4;
typedef __attribute__((ext_vector_type(16))) float f32x16;

typedef __attribute__((address_space(1))) unsigned int guint;
typedef __attribute__((address_space(3))) unsigned int luint;

#define MFMA16 __builtin_amdgcn_mfma_f32_16x16x32_bf16
#define MFMA32 __builtin_amdgcn_mfma_f32_32x32x16_bf16

__device__ __forceinline__ void gl_lds16(const void* g, void* l) {
  __builtin_amdgcn_global_load_lds((guint*)(unsigned long long)g,
                                   (luint*)(unsigned)(unsigned long long)l,
                                   16, 0, 0);
}

__device__ __forceinline__ unsigned cvtpk(float lo, float hi) {
  unsigned r;
  asm("v_cvt_pk_bf16_f32 %0, %1, %2" : "=v"(r) : "v"(lo), "v"(hi));
  return r;
}
__device__ __forceinline__ void plswap(unsigned& a, unsigned& b) {
  asm volatile("v_permlane32_swap_b32 %0, %1" : "+v"(a), "+v"(b));
}
__device__ __forceinline__ bf16x8 mk8(unsigned d0, unsigned d1, unsigned d2, unsigned d3) {
  union { unsigned u[4]; bf16x8 v; } x;
  x.u[0] = d0; x.u[1] = d1; x.u[2] = d2; x.u[3] = d3;
  return x.v;
}

// ---------------- mask interval precompute ----------------
__global__ __launch_bounds__(256) void mask_prep(const int* __restrict__ tokens,
                                                 const unsigned char* __restrict__ seg,
                                                 const unsigned char* __restrict__ spc,
                                                 int4* __restrict__ mi) {
  __shared__ int ssp[257], ssg[257];
  __shared__ int slay;
  int t = threadIdx.x;
  if (t == 0) {
    int nz = 0, f32c = 0;
    for (int i = 0; i < 256; i++) {
      if ((i & 3) != 0 && seg[i]) nz++;
      if ((i & 3) == 3 && seg[i] == 0x3f) f32c++;
    }
    slay = (f32c > 8) ? 2 : ((nz > 4) ? 1 : 0);
  }
  __syncthreads();
  int lay = slay;
  auto getb = [&](const unsigned char* p, int i) -> int {
    if (lay == 1) return p[i] != 0;
    if (lay == 2) return ((const float*)p)[i] != 0.f;
    return ((const int*)p)[i] != 0;
  };
  int base = t * 8, a = 0, b = 0;
  for (int j = 0; j < 8; j++) { a += getb(spc, base + j); b += 1 - getb(seg, base + j); }
  ssp[t + 1] = a; ssg[t + 1] = b;
  __syncthreads();
  if (t == 0) {
    ssp[0] = 0; ssg[0] = 0;
    for (int i = 1; i <= 256; i++) { ssp[i] += ssp[i - 1]; ssg[i] += ssg[i - 1]; }
  }
  __syncthreads();
  int esp = ssp[t], esg = ssg[t];
  for (int j = 0; j < 8; j++) {
    int i = base + j;
    int sp = getb(spc, i), sg = 1 - getb(seg, i);
    int np = (tokens[i] != 127) ? 1 : 0;
    int wint = (i == 0) ? (1 + sp) : (1 + esp);
    int sint = (i == 0) ? (1 + sg) : (1 + esg);
    mi[i] = make_int4(np | (sp << 1) | (sg << 2), wint, sint, 0);
    esp += sp; esg += sg;
  }
}

// ---------------- full mask bit table: cmask[word][q], word=kv/32 ----------------
__global__ __launch_bounds__(256) void bitgen(const int4* __restrict__ mi,
                                              unsigned* __restrict__ cmask) {
  __shared__ int4 km[32];
  int w = blockIdx.x;
  int t = threadIdx.x;
  int q = blockIdx.y * 256 + t;
  if (t < 32) km[t] = mi[w * 32 + t];
  __syncthreads();
  int4 mq = mi[q];
  unsigned word = 0;
  #pragma unroll
  for (int j = 0; j < 32; j++) {
    int kv = w * 32 + j;
    int4 mk = km[j];
    bool v = ((mq.x & mk.x) & 1) &&
             ((mk.x & 2) || (mq.y == mk.y)) &&
             ((mk.x & 4) || (mq.z == mk.z)) &&
             (kv <= q);
    word |= (v ? 1u : 0u) << j;
  }
  cmask[(size_t)w * S + q] = word;
}

// ---------------- shared transpose-store helper ----------------
__device__ __forceinline__ void store_h_hT(bf16x8 ob[4], bf16_t* tile, int q0, int h,
                                           int ql, int d0, int tid,
                                           bf16_t* __restrict__ hb, bf16_t* __restrict__ hbT) {
  #pragma unroll
  for (int i = 0; i < 4; i++)
    *(bf16x8*)(hb + (size_t)(q0 + ql) * HID + h * DH + d0 + i * 8) = ob[i];
  #pragma unroll
  for (int i = 0; i < 4; i++)
    #pragma unroll
    for (int j = 0; j < 8; j++) tile[ql * 136 + d0 + i * 8 + j] = ob[i][j];
  __syncthreads();
  int dT = tid >> 1, qh = (tid & 1) * 32;
  bf16x8 tb[4];
  #pragma unroll
  for (int i = 0; i < 4; i++)
    #pragma unroll
    for (int j = 0; j < 8; j++) tb[i][j] = tile[(qh + i * 8 + j) * 136 + dT];
  #pragma unroll
  for (int i = 0; i < 4; i++)
    *(bf16x8*)(hbT + (size_t)(h * DH + dT) * S + q0 + qh + i * 8) = tb[i];
}

// ---------------- embedding gather -> bf16 h and h^T ----------------
__global__ __launch_bounds__(256) void embedT(const int* __restrict__ tokens,
                                              const float* __restrict__ emb,
                                              bf16_t* __restrict__ hb, bf16_t* __restrict__ hbT) {
  __shared__ bf16_t tile[64 * 136];
  int tid = threadIdx.x;
  int q0 = blockIdx.x * 64, h = blockIdx.y;
  int ql = tid >> 2, d0 = (tid & 3) * 32;
  int tok = tokens[q0 + ql];
  const float4* src = (const float4*)(emb + (size_t)tok * HID + h * DH + d0);
  bf16x8 ob[4];
  #pragma unroll
  for (int i = 0; i < 8; i++) {
    float4 f = src[i];
    ob[i >> 1][(i & 1) * 4 + 0] = (bf16_t)f.x;
    ob[i >> 1][(i & 1) * 4 + 1] = (bf16_t)f.y;
    ob[i >> 1][(i & 1) * 4 + 2] = (bf16_t)f.z;
    ob[i >> 1][(i & 1) * 4 + 3] = (bf16_t)f.w;
  }
  store_h_hT(ob, tile, q0, h, ql, d0, tid, hb, hbT);
}

// ---------------- combine 2 kv-split partials -> bf16 h and h^T (in place) ----------------
__global__ __launch_bounds__(256) void combine_k(const bf16_t* __restrict__ OP,
                                                 const float2* __restrict__ ml,
                                                 bf16_t* __restrict__ hb, bf16_t* __restrict__ hbT) {
  __shared__ bf16_t tile[64 * 136];
  int tid = threadIdx.x;
  int q0 = blockIdx.x * 64, h = blockIdx.y;
  int ql = tid >> 2, d0 = (tid & 3) * 32;
  int q = q0 + ql;
  float2 a = ml[(size_t)h * S + q];
  float2 b = ml[(size_t)(NH + h) * S + q];
  float M = fmaxf(a.x, b.x);
  float c1 = exp2f((a.x - M) * K2EXP), c2 = exp2f((b.x - M) * K2EXP);
  float lt = a.y * c1 + b.y * c2;
  float inv = lt > 0.f ? 1.f / lt : 0.f;
  c1 *= inv; c2 *= inv;
  const bf16x8* o1 = (const bf16x8*)(OP + ((size_t)h * S + q) * DH + d0);
  const bf16x8* o2 = (const bf16x8*)(OP + ((size_t)(NH + h) * S + q) * DH + d0);
  bf16x8 ob[4];
  #pragma unroll
  for (int i = 0; i < 4; i++) {
    bf16x8 x = o1[i], y = o2[i];
    #pragma unroll
    for (int j = 0; j < 8; j++)
      ob[i][j] = (bf16_t)((float)x[j] * c1 + (float)y[j] * c2);
  }
  store_h_hT(ob, tile, q0, h, ql, d0, tid, hb, hbT);
}

// ---------------- attention partial: 128-q stripe per block, kv-split z ----------------
__global__ __launch_bounds__(256, 2) void attn3(const bf16_t* __restrict__ hb,
                                                const bf16_t* __restrict__ hbT,
                                                const unsigned* __restrict__ cmask,
                                                bf16_t* __restrict__ OP,
                                                float2* __restrict__ ml) {
  __shared__ __align__(16) char lds_raw[65536];

  int h = blockIdx.x;
  int bt = 15 - (int)blockIdx.y;   // big stripes dispatch first
  int z = blockIdx.z;
  int tid = threadIdx.x, w = tid >> 6, l = tid & 63, l31 = l & 31, hi = l >> 5;
  int q0w = 128 * bt + 32 * w, q = q0w + l31;

  // Q fragments (B operand): lane holds Q[q=l31][d = 16ks + 8hi + j]
  bf16x8 qf[8];
  {
    const bf16_t* hq = hb + (size_t)q * HID + h * DH;
    #pragma unroll
    for (int ks = 0; ks < 8; ks++) qf[ks] = *(const bf16x8*)(hq + ks * 16 + hi * 8);
  }

  f32x16 acc[4];
  #pragma unroll
  for (int i = 0; i < 4; i++)
    #pragma unroll
    for (int r = 0; r < 16; r++) acc[i][r] = 0.f;
  float m = -1e30f, lsum = 0.f;
  int swz = l31 & 7;
  int nIter = bt + 1;

  auto STAGE = [&](int t, int b) {
    int kv0 = t * 64;
    bf16_t* Kb = (bf16_t*)(lds_raw + b * 16384);
    bf16_t* Vb = (bf16_t*)(lds_raw + 32768 + b * 16384);
    #pragma unroll
    for (int i = 0; i < 4; i++) {
      int seg = w * 4 + i;
      int row = seg * 4 + (l >> 4);
      int ch = (l & 15) ^ (row & 7);
      gl_lds16(hb + (size_t)(kv0 + row) * HID + h * DH + ch * 8, Kb + seg * 512);
    }
    #pragma unroll
    for (int i = 0; i < 4; i++) {
      int seg = w * 4 + i;
      int row = seg * 8 + (l >> 3);
      int ch = (l & 7) ^ (row & 7);
      gl_lds16(hbT + (size_t)(h * DH + row) * S + kv0 + ch * 8, Vb + seg * 512);
    }
  };

  STAGE(z, 0);
  for (int i = 0; i < nIter; i++) {
    int t = z + 2 * i;
    int b = i & 1;
    unsigned w0 = cmask[(size_t)(2 * t) * S + q];
    unsigned w1 = cmask[(size_t)(2 * t + 1) * S + q];
    if (i + 1 < nIter) {
      STAGE(t + 2, b ^ 1);
      asm volatile("s_waitcnt vmcnt(8)" ::: "memory");
    } else {
      asm volatile("s_waitcnt vmcnt(0)" ::: "memory");
    }
    __builtin_amdgcn_s_barrier();
    __builtin_amdgcn_sched_barrier(0);

    const bf16_t* Kb = (const bf16_t*)(lds_raw + b * 16384);
    const bf16_t* Vb = (const bf16_t*)(lds_raw + 32768 + b * 16384);
    // QK^T swapped: D[kv][q], two 32-kv blocks
    f32x16 s0, s1;
    #pragma unroll
    for (int r = 0; r < 16; r++) { s0[r] = 0.f; s1[r] = 0.f; }
    const bf16_t* k0p = Kb + l31 * 128;
    const bf16_t* k1p = Kb + (32 + l31) * 128;
    #pragma unroll
    for (int ks = 0; ks < 8; ks++) {
      int ch = ((2 * ks + hi) ^ swz) * 8;
      bf16x8 kf0 = *(const bf16x8*)(k0p + ch);
      bf16x8 kf1 = *(const bf16x8*)(k1p + ch);
      s0 = MFMA32(kf0, qf[ks], s0, 0, 0, 0);
      s1 = MFMA32(kf1, qf[ks], s1, 0, 0, 0);
    }

    float sv0[16], sv1[16];
    float mx = NEGS;
    #pragma unroll
    for (int r = 0; r < 16; r++) {
      int bit = (r & 3) + 8 * (r >> 2) + 4 * hi;
      sv0[r] = ((w0 >> bit) & 1u) ? s0[r] : NEGS;
      sv1[r] = ((w1 >> bit) & 1u) ? s1[r] : NEGS;
      mx = fmaxf(mx, fmaxf(sv0[r], sv1[r]));
    }
    mx = fmaxf(mx, __shfl_xor(mx, 32, 64));
    if (__any(mx > m + RTHR)) {
      float mn = fmaxf(m, mx);
      float al = exp2f((m - mn) * K2EXP);
      m = mn; lsum *= al;
      #pragma unroll
      for (int r = 0; r < 16; r++) {
        float alr = __shfl(al, (r & 3) + 8 * (r >> 2) + 4 * hi, 64);
        #pragma unroll
        for (int d = 0; d < 4; d++) acc[d][r] *= alr;
      }
    }
    float mk = m * K2EXP;
    float p0[16], p1[16], ps = 0.f;
    #pragma unroll
    for (int r = 0; r < 16; r++) {
      p0[r] = exp2f(__builtin_fmaf(sv0[r], K2EXP, -mk));
      p1[r] = exp2f(__builtin_fmaf(sv1[r], K2EXP, -mk));
      ps += p0[r] + p1[r];
    }
    ps += __shfl_xor(ps, 32, 64);
    lsum += ps;

    // pack P -> A-fragments via cvt_pk + permlane32_swap (T12)
    bf16x8 pa[4];
    {
      unsigned a0 = cvtpk(p0[0], p0[1]),  a1 = cvtpk(p0[2], p0[3]);
      unsigned b0 = cvtpk(p0[4], p0[5]),  b1 = cvtpk(p0[6], p0[7]);
      unsigned a2 = cvtpk(p0[8], p0[9]),  a3 = cvtpk(p0[10], p0[11]);
      unsigned b2 = cvtpk(p0[12], p0[13]), b3 = cvtpk(p0[14], p0[15]);
      plswap(a0, b0); plswap(a1, b1); plswap(a2, b2); plswap(a3, b3);
      pa[0] = mk8(a0, a1, b0, b1);
      pa[1] = mk8(a2, a3, b2, b3);
      unsigned c0 = cvtpk(p1[0], p1[1]),  c1 = cvtpk(p1[2], p1[3]);
      unsigned d0 = cvtpk(p1[4], p1[5]),  d1 = cvtpk(p1[6], p1[7]);
      unsigned c2 = cvtpk(p1[8], p1[9]),  c3 = cvtpk(p1[10], p1[11]);
      unsigned d2 = cvtpk(p1[12], p1[13]), d3 = cvtpk(p1[14], p1[15]);
      plswap(c0, d0); plswap(c1, d1); plswap(c2, d2); plswap(c3, d3);
      pa[2] = mk8(c0, c1, d0, d1);
      pa[3] = mk8(c2, c3, d2, d3);
    }

    // PV: O[q][d] += P V, 4 d-blocks of 32
    #pragma unroll
    for (int db = 0; db < 4; db++) {
      const bf16_t* vr = Vb + (32 * db + l31) * 64;
      #pragma unroll
      for (int ks = 0; ks < 4; ks++) {
        bf16x8 vf = *(const bf16x8*)(vr + ((2 * ks + hi) ^ swz) * 8);
        acc[db] = MFMA32(pa[ks], vf, acc[db], 0, 0, 0);
      }
    }
    __builtin_amdgcn_s_barrier();
  }

  // epilogue: store unnormalized partial + (m, l)
  size_t obase = ((size_t)(z * NH + h) * S + q0w) * DH;
  #pragma unroll
  for (int r = 0; r < 16; r++) {
    int qr = (r & 3) + 8 * (r >> 2) + 4 * hi;
    #pragma unroll
    for (int db = 0; db < 4; db++)
      OP[obase + (size_t)qr * DH + db * 32 + l31] = (bf16_t)acc[db][r];
  }
  if (hi == 0) ml[(size_t)(z * NH + h) * S + q] = make_float2(m, lsum);
}

// ---------------- lm head ----------------
__global__ __launch_bounds__(256) void wcvt(const float* __restrict__ w, bf16_t* __restrict__ wb) {
  int i = blockIdx.x * 256 + threadIdx.x;
  float4 f = ((const float4*)w)[i];
  bf16x4 v;
  v[0] = (bf16_t)f.x; v[1] = (bf16_t)f.y; v[2] = (bf16_t)f.z; v[3] = (bf16_t)f.w;
  *(bf16x4*)(wb + (size_t)i * 4) = v;
}

__global__ __launch_bounds__(256) void lm_head(const bf16_t* __restrict__ hb,
                                               const bf16_t* __restrict__ wbf,
                                               const float* __restrict__ bias,
                                               float* __restrict__ out) {
  __shared__ float red[4][16][130];
  int tid = threadIdx.x;
  int w = tid >> 6, l = tid & 63, l16 = l & 15, g = l >> 4;
  int t0 = blockIdx.x * 16;
  f32x4 acc[8];
  #pragma unroll
  for (int i = 0; i < 8; i++) acc[i] = (f32x4){0.f, 0.f, 0.f, 0.f};
  const bf16_t* arow = hb + (size_t)(t0 + l16) * HID + w * 512;
  for (int k0 = 0; k0 < 512; k0 += 32) {
    bf16x8 af = *(const bf16x8*)(arow + k0 + g * 8);
    #pragma unroll
    for (int vt = 0; vt < 8; vt++) {
      bf16x8 bf_ = *(const bf16x8*)(wbf + (size_t)(vt * 16 + l16) * HID + w * 512 + k0 + g * 8);
      acc[vt] = MFMA16(af, bf_, acc[vt], 0, 0, 0);
    }
  }
  #pragma unroll
  for (int vt = 0; vt < 8; vt++)
    #pragma unroll
    for (int r = 0; r < 4; r++)
      red[w][4 * g + r][vt * 16 + l16] = acc[vt][r];
  __syncthreads();
  int q = tid >> 4, vc = (tid & 15) * 8;
  #pragma unroll
  for (int j = 0; j < 8; j++) {
    float s = red[0][q][vc + j] + red[1][q][vc + j] + red[2][q][vc + j] + red[3][q][vc + j];
    out[(size_t)(t0 + q) * VOC + vc + j] = s + bias[vc + j];
  }
}

// ---------------- segment head (bf16 hidden) ----------------
__global__ __launch_bounds__(256) void seg_head(const bf16_t* __restrict__ hb,
                                                const float* __restrict__ sw,
                                                const float* __restrict__ sb,
                                                float* __restrict__ out) {
  int tid = threadIdx.x;
  int token = blockIdx.x * 8 + (tid >> 5);
  int lane = tid & 31;
  const bf16x8* hr = (const bf16x8*)(hb + (size_t)token * HID);
  const float4* w0 = (const float4*)sw;
  const float4* w1 = (const float4*)(sw + HID);
  float a0 = 0.f, a1 = 0.f;
  #pragma unroll
  for (int i = 0; i < 8; i++) {
    int c = lane + i * 32;
    bf16x8 v = hr[c];
    float4 x0 = w0[c * 2], x1 = w0[c * 2 + 1];
    float4 y0 = w1[c * 2], y1 = w1[c * 2 + 1];
    a0 += (float)v[0]*x0.x + (float)v[1]*x0.y + (float)v[2]*x0.z + (float)v[3]*x0.w
        + (float)v[4]*x1.x + (float)v[5]*x1.y + (float)v[6]*x1.z + (float)v[7]*x1.w;
    a1 += (float)v[0]*y0.x + (float)v[1]*y0.y + (float)v[2]*y0.z + (float)v[3]*y0.w
        + (float)v[4]*y1.x + (float)v[5]*y1.y + (float)v[6]*y1.z + (float)v[7]*y1.w;
  }
  #pragma unroll
  for (int off = 16; off; off >>= 1) {
    a0 += __shfl_xor(a0, off, 64);
    a1 += __shfl_xor(a1, off, 64);
  }
  if (lane == 0) {
    out[(size_t)token * 2] = a0 + sb[0];
    out[(size_t)token * 2 + 1] = a1 + sb[1];
  }
}

extern "C" void kernel_launch(void* const* d_in, const int* in_sizes, int n_in,
                              void* d_out, int out_size, void* d_ws, size_t ws_size,
                              hipStream_t stream) {
  const int* tokens = (const int*)d_in[0];
  const unsigned char* seg = (const unsigned char*)d_in[1];
  const unsigned char* spc = (const unsigned char*)d_in[2];
  const float* emb_w = (const float*)d_in[3];
  const float* lm_w = (const float*)d_in[4];
  const float* lm_b = (const float*)d_in[5];
  const float* seg_w = (const float*)d_in[6];
  const float* seg_b = (const float*)d_in[7];

  char* ws = (char*)d_ws;
  int4* mi = (int4*)ws;                                  // 32KB  @0
  unsigned* cmask = (unsigned*)(ws + (1u << 20));        // 512KB @1MB
  float2* ml = (float2*)(ws + (2u << 20));               // 512KB @2MB
  bf16_t* wbf = (bf16_t*)(ws + (3u << 20));              // 512KB @3MB
  bf16_t* hb  = (bf16_t*)(ws + (4u << 20));              // 8MB   @4MB
  bf16_t* hbT = (bf16_t*)(ws + (12u << 20));             // 8MB   @12MB
  bf16_t* OP  = (bf16_t*)(ws + (20u << 20));             // 16MB  @20MB
  float* out = (float*)d_out;

  mask_prep<<<1, 256, 0, stream>>>(tokens, seg, spc, mi);
  bitgen<<<dim3(64, 8), 256, 0, stream>>>(mi, cmask);
  embedT<<<dim3(S / 64, NH), 256, 0, stream>>>(tokens, emb_w, hb, hbT);

  for (int L = 0; L < 4; L++) {
    attn3<<<dim3(NH, 16, 2), 256, 0, stream>>>(hb, hbT, cmask, OP, ml);
    combine_k<<<dim3(S / 64, NH), 256, 0, stream>>>(OP, ml, hb, hbT);
  }

  wcvt<<<(VOC * HID / 4) / 256, 256, 0, stream>>>(lm_w, wbf);
  lm_head<<<S / 16, 256, 0, stream>>>(hb, wbf, lm_b, out);
  seg_head<<<S / 8, 256, 0, stream>>>(hb, seg_w, seg_b, out + (size_t)S * VOC);
}

// Round 6
// 211.178 us; speedup vs baseline: 1.9960x; 1.6130x over previous
//
#include <hip/hip_runtime.h>

#define S 2048
#define HID 2048
#define NH 16
#define DH 128
#define VOC 128
#define NZ 3
#define K2EXP 0.12752551286084112f   // (1/sqrt(128)) * log2(e)
#define RTHR 62.0f                   // defer-max threshold in raw-score units
#define NEGS -3.0e38f

typedef __bf16 bf16_t;
typedef __attribute__((ext_vector_type(8))) __bf16 bf16x8;
typedef __attribute__((ext_vector_type(4))) __bf16 bf16x4;
typedef __attribute__((ext_vector_type(4))) float f32x4;
typedef __attribute__((ext_vector_type(16))) float f32x16;

typedef __attribute__((address_space(1))) unsigned int guint;
typedef __attribute__((address_space(3))) unsigned int luint;

#define MFMA16 __builtin_amdgcn_mfma_f32_16x16x32_bf16
#define MFMA32 __builtin_amdgcn_mfma_f32_32x32x16_bf16

__device__ __forceinline__ void gl_lds16(const void* g, void* l) {
  __builtin_amdgcn_global_load_lds((guint*)(unsigned long long)g,
                                   (luint*)(unsigned)(unsigned long long)l,
                                   16, 0, 0);
}

__device__ __forceinline__ unsigned cvtpk(float lo, float hi) {
  unsigned r;
  asm("v_cvt_pk_bf16_f32 %0, %1, %2" : "=v"(r) : "v"(lo), "v"(hi));
  return r;
}
__device__ __forceinline__ void plswap(unsigned& a, unsigned& b) {
  asm volatile("v_permlane32_swap_b32 %0, %1" : "+v"(a), "+v"(b));
}
__device__ __forceinline__ bf16x8 mk8(unsigned d0, unsigned d1, unsigned d2, unsigned d3) {
  union { unsigned u[4]; bf16x8 v; } x;
  x.u[0] = d0; x.u[1] = d1; x.u[2] = d2; x.u[3] = d3;
  return x.v;
}

// ---------------- mask interval precompute (parallel scan) ----------------
__global__ __launch_bounds__(256) void mask_prep(const int* __restrict__ tokens,
                                                 const unsigned char* __restrict__ seg,
                                                 const unsigned char* __restrict__ spc,
                                                 int4* __restrict__ mi) {
  __shared__ int ssp[257], ssg[257];
  __shared__ int cdet[2];
  int t = threadIdx.x;
  if (t < 2) cdet[t] = 0;
  __syncthreads();
  {
    int nz = ((t & 3) != 0 && seg[t]) ? 1 : 0;
    int fc = ((t & 3) == 3 && seg[t] == 0x3f) ? 1 : 0;
    if (nz) atomicAdd(&cdet[0], 1);
    if (fc) atomicAdd(&cdet[1], 1);
  }
  __syncthreads();
  int lay = (cdet[1] > 8) ? 2 : ((cdet[0] > 4) ? 1 : 0);
  auto getb = [&](const unsigned char* p, int i) -> int {
    if (lay == 1) return p[i] != 0;
    if (lay == 2) return ((const float*)p)[i] != 0.f;
    return ((const int*)p)[i] != 0;
  };
  int base = t * 8, a = 0, b = 0;
  for (int j = 0; j < 8; j++) { a += getb(spc, base + j); b += 1 - getb(seg, base + j); }
  ssp[t + 1] = a; ssg[t + 1] = b;
  if (t == 0) { ssp[0] = 0; ssg[0] = 0; }
  __syncthreads();
  for (int off = 1; off < 256; off <<= 1) {
    int v = 0, u = 0;
    if (t + 1 > off) { v = ssp[t + 1 - off]; u = ssg[t + 1 - off]; }
    __syncthreads();
    ssp[t + 1] += v; ssg[t + 1] += u;
    __syncthreads();
  }
  int esp = ssp[t], esg = ssg[t];
  for (int j = 0; j < 8; j++) {
    int i = base + j;
    int sp = getb(spc, i), sg = 1 - getb(seg, i);
    int np = (tokens[i] != 127) ? 1 : 0;
    int wint = (i == 0) ? (1 + sp) : (1 + esp);
    int sint = (i == 0) ? (1 + sg) : (1 + esg);
    mi[i] = make_int4(np | (sp << 1) | (sg << 2), wint, sint, 0);
    esp += sp; esg += sg;
  }
}

// ---------------- full mask bit table: cmask[word][q], word=kv/32 ----------------
__global__ __launch_bounds__(256) void bitgen(const int4* __restrict__ mi,
                                              unsigned* __restrict__ cmask) {
  __shared__ int4 km[32];
  int w = blockIdx.x;
  int t = threadIdx.x;
  int q = blockIdx.y * 256 + t;
  if (t < 32) km[t] = mi[w * 32 + t];
  __syncthreads();
  int4 mq = mi[q];
  unsigned word = 0;
  #pragma unroll
  for (int j = 0; j < 32; j++) {
    int kv = w * 32 + j;
    int4 mk = km[j];
    bool v = ((mq.x & mk.x) & 1) &&
             ((mk.x & 2) || (mq.y == mk.y)) &&
             ((mk.x & 4) || (mq.z == mk.z)) &&
             (kv <= q);
    word |= (v ? 1u : 0u) << j;
  }
  cmask[(size_t)w * S + q] = word;
}

// ---------------- active-tile list per 128-q stripe ----------------
__global__ __launch_bounds__(256) void tprep(const unsigned* __restrict__ cmask,
                                             int* __restrict__ tilecnt,
                                             int* __restrict__ tilelist) {
  __shared__ int act[32];
  __shared__ int lst[32];
  __shared__ int scnt;
  int st = blockIdx.x;              // stripe 0..15
  int tid = threadIdx.x;
  int t = tid >> 3;                 // tile 0..31 (64 kv each)
  int s8 = tid & 7;
  unsigned o = 0;
  if (t <= 2 * st + 1) {
    #pragma unroll
    for (int j = 0; j < 16; j++) {
      int q = 128 * st + s8 * 16 + j;
      o |= cmask[(size_t)(2 * t) * S + q] | cmask[(size_t)(2 * t + 1) * S + q];
    }
  }
  o |= __shfl_xor(o, 1, 64);
  o |= __shfl_xor(o, 2, 64);
  o |= __shfl_xor(o, 4, 64);
  if (s8 == 0) act[t] = (o != 0) ? 1 : 0;
  __syncthreads();
  if (tid == 0) {
    int c = 0;
    for (int i = 0; i < 32; i++) if (act[i]) lst[c++] = i;
    tilecnt[st] = c; scnt = c;
  }
  __syncthreads();
  if (tid < 32) tilelist[st * 32 + tid] = (tid < scnt) ? lst[tid] : 0;
}

// ---------------- shared transpose-store helper ----------------
__device__ __forceinline__ void store_h_hT(bf16x8 ob[4], bf16_t* tile, int q0, int h,
                                           int ql, int d0, int tid,
                                           bf16_t* __restrict__ hb, bf16_t* __restrict__ hbT) {
  #pragma unroll
  for (int i = 0; i < 4; i++)
    *(bf16x8*)(hb + (size_t)(q0 + ql) * HID + h * DH + d0 + i * 8) = ob[i];
  #pragma unroll
  for (int i = 0; i < 4; i++)
    #pragma unroll
    for (int j = 0; j < 8; j++) tile[ql * 136 + d0 + i * 8 + j] = ob[i][j];
  __syncthreads();
  int dT = tid >> 1, qh = (tid & 1) * 32;
  bf16x8 tb[4];
  #pragma unroll
  for (int i = 0; i < 4; i++)
    #pragma unroll
    for (int j = 0; j < 8; j++) tb[i][j] = tile[(qh + i * 8 + j) * 136 + dT];
  #pragma unroll
  for (int i = 0; i < 4; i++)
    *(bf16x8*)(hbT + (size_t)(h * DH + dT) * S + q0 + qh + i * 8) = tb[i];
}

// ---------------- embedding gather -> bf16 h and h^T ----------------
__global__ __launch_bounds__(256) void embedT(const int* __restrict__ tokens,
                                              const float* __restrict__ emb,
                                              bf16_t* __restrict__ hb, bf16_t* __restrict__ hbT) {
  __shared__ bf16_t tile[64 * 136];
  int tid = threadIdx.x;
  int q0 = blockIdx.x * 64, h = blockIdx.y;
  int ql = tid >> 2, d0 = (tid & 3) * 32;
  int tok = tokens[q0 + ql];
  const float4* src = (const float4*)(emb + (size_t)tok * HID + h * DH + d0);
  bf16x8 ob[4];
  #pragma unroll
  for (int i = 0; i < 8; i++) {
    float4 f = src[i];
    ob[i >> 1][(i & 1) * 4 + 0] = (bf16_t)f.x;
    ob[i >> 1][(i & 1) * 4 + 1] = (bf16_t)f.y;
    ob[i >> 1][(i & 1) * 4 + 2] = (bf16_t)f.z;
    ob[i >> 1][(i & 1) * 4 + 3] = (bf16_t)f.w;
  }
  store_h_hT(ob, tile, q0, h, ql, d0, tid, hb, hbT);
}

// ---------------- combine up to NZ kv-split partials -> bf16 h and h^T ----------------
__global__ __launch_bounds__(256) void combine_k(const bf16_t* __restrict__ OP,
                                                 const float2* __restrict__ ml,
                                                 const int* __restrict__ tilecnt,
                                                 bf16_t* __restrict__ hb, bf16_t* __restrict__ hbT) {
  __shared__ bf16_t tile[64 * 136];
  int tid = threadIdx.x;
  int q0 = blockIdx.x * 64, h = blockIdx.y;
  int ql = tid >> 2, d0 = (tid & 3) * 32;
  int q = q0 + ql;
  int st = q0 >> 7;
  int cnt = tilecnt[st];
  int npart = cnt < NZ ? cnt : NZ;
  float M = -1e30f, L = 0.f;
  float o[32];
  #pragma unroll
  for (int i = 0; i < 32; i++) o[i] = 0.f;
  for (int p = 0; p < npart; p++) {
    float2 a = ml[(size_t)(p * NH + h) * S + q];
    float Mn = fmaxf(M, a.x);
    float sc = exp2f((M - Mn) * K2EXP);
    float wp = exp2f((a.x - Mn) * K2EXP);
    L = L * sc + a.y * wp;
    const bf16x8* op = (const bf16x8*)(OP + ((size_t)(p * NH + h) * S + q) * DH + d0);
    #pragma unroll
    for (int i = 0; i < 4; i++) {
      bf16x8 x = op[i];
      #pragma unroll
      for (int j = 0; j < 8; j++)
        o[i * 8 + j] = o[i * 8 + j] * sc + (float)x[j] * wp;
    }
    M = Mn;
  }
  float inv = L > 0.f ? 1.f / L : 0.f;
  bf16x8 ob[4];
  #pragma unroll
  for (int i = 0; i < 4; i++)
    #pragma unroll
    for (int j = 0; j < 8; j++)
      ob[i][j] = (bf16_t)(o[i * 8 + j] * inv);
  store_h_hT(ob, tile, q0, h, ql, d0, tid, hb, hbT);
}

// ---------------- attention partial: 128-q stripe, compacted active tiles ----------------
__global__ __launch_bounds__(256, 2) void attn3(const bf16_t* __restrict__ hb,
                                                const bf16_t* __restrict__ hbT,
                                                const unsigned* __restrict__ cmask,
                                                const int* __restrict__ tilecnt,
                                                const int* __restrict__ tilelist,
                                                bf16_t* __restrict__ OP,
                                                float2* __restrict__ ml) {
  __shared__ __align__(16) char lds_raw[65536];

  int h = blockIdx.x;
  int bt = 15 - (int)blockIdx.y;   // big stripes dispatch first
  int z = blockIdx.z;
  int cnt = tilecnt[bt];
  int nIter = (cnt > z) ? ((cnt - z + NZ - 1) / NZ) : 0;
  if (nIter == 0) return;

  int tid = threadIdx.x, w = tid >> 6, l = tid & 63, l31 = l & 31, hi = l >> 5;
  int q0w = 128 * bt + 32 * w, q = q0w + l31;

  bf16x8 qf[8];
  {
    const bf16_t* hq = hb + (size_t)q * HID + h * DH;
    #pragma unroll
    for (int ks = 0; ks < 8; ks++) qf[ks] = *(const bf16x8*)(hq + ks * 16 + hi * 8);
  }

  f32x16 acc[4];
  #pragma unroll
  for (int i = 0; i < 4; i++)
    #pragma unroll
    for (int r = 0; r < 16; r++) acc[i][r] = 0.f;
  float m = -1e30f, lsum = 0.f;
  int swz = l31 & 7;

  auto STAGE = [&](int t, int b) {
    int kv0 = t * 64;
    bf16_t* Kb = (bf16_t*)(lds_raw + b * 16384);
    bf16_t* Vb = (bf16_t*)(lds_raw + 32768 + b * 16384);
    #pragma unroll
    for (int i = 0; i < 4; i++) {
      int sg = w * 4 + i;
      int row = sg * 4 + (l >> 4);
      int ch = (l & 15) ^ (row & 7);
      gl_lds16(hb + (size_t)(kv0 + row) * HID + h * DH + ch * 8, Kb + sg * 512);
    }
    #pragma unroll
    for (int i = 0; i < 4; i++) {
      int sg = w * 4 + i;
      int row = sg * 8 + (l >> 3);
      int ch = (l & 7) ^ (row & 7);
      gl_lds16(hbT + (size_t)(h * DH + row) * S + kv0 + ch * 8, Vb + sg * 512);
    }
  };

  int tcur = tilelist[bt * 32 + z];
  STAGE(tcur, 0);
  for (int i = 0; i < nIter; i++) {
    int b = i & 1;
    int t = tcur;
    unsigned w0 = cmask[(size_t)(2 * t) * S + q];
    unsigned w1 = cmask[(size_t)(2 * t + 1) * S + q];
    int knext = z + NZ * (i + 1);
    if (knext < cnt) {
      int tnext = tilelist[bt * 32 + knext];
      STAGE(tnext, b ^ 1);
      tcur = tnext;
      asm volatile("s_waitcnt vmcnt(8)" ::: "memory");
    } else {
      asm volatile("s_waitcnt vmcnt(0)" ::: "memory");
    }
    __builtin_amdgcn_s_barrier();
    __builtin_amdgcn_sched_barrier(0);

    const bf16_t* Kb = (const bf16_t*)(lds_raw + b * 16384);
    const bf16_t* Vb = (const bf16_t*)(lds_raw + 32768 + b * 16384);
    f32x16 s0, s1;
    #pragma unroll
    for (int r = 0; r < 16; r++) { s0[r] = 0.f; s1[r] = 0.f; }
    const bf16_t* k0p = Kb + l31 * 128;
    const bf16_t* k1p = Kb + (32 + l31) * 128;
    #pragma unroll
    for (int ks = 0; ks < 8; ks++) {
      int ch = ((2 * ks + hi) ^ swz) * 8;
      bf16x8 kf0 = *(const bf16x8*)(k0p + ch);
      bf16x8 kf1 = *(const bf16x8*)(k1p + ch);
      s0 = MFMA32(kf0, qf[ks], s0, 0, 0, 0);
      s1 = MFMA32(kf1, qf[ks], s1, 0, 0, 0);
    }

    float sv0[16], sv1[16];
    float mx = NEGS;
    #pragma unroll
    for (int r = 0; r < 16; r++) {
      int bit = (r & 3) + 8 * (r >> 2) + 4 * hi;
      sv0[r] = ((w0 >> bit) & 1u) ? s0[r] : NEGS;
      sv1[r] = ((w1 >> bit) & 1u) ? s1[r] : NEGS;
      mx = fmaxf(mx, fmaxf(sv0[r], sv1[r]));
    }
    mx = fmaxf(mx, __shfl_xor(mx, 32, 64));
    if (__any(mx > m + RTHR)) {
      float mn = fmaxf(m, mx);
      float al = exp2f((m - mn) * K2EXP);
      m = mn; lsum *= al;
      #pragma unroll
      for (int r = 0; r < 16; r++) {
        float alr = __shfl(al, (r & 3) + 8 * (r >> 2) + 4 * hi, 64);
        #pragma unroll
        for (int d = 0; d < 4; d++) acc[d][r] *= alr;
      }
    }
    float mk = m * K2EXP;
    float p0[16], p1[16], ps = 0.f;
    #pragma unroll
    for (int r = 0; r < 16; r++) {
      p0[r] = exp2f(__builtin_fmaf(sv0[r], K2EXP, -mk));
      p1[r] = exp2f(__builtin_fmaf(sv1[r], K2EXP, -mk));
      ps += p0[r] + p1[r];
    }
    ps += __shfl_xor(ps, 32, 64);
    lsum += ps;

    bf16x8 pa[4];
    {
      unsigned a0 = cvtpk(p0[0], p0[1]),  a1 = cvtpk(p0[2], p0[3]);
      unsigned b0 = cvtpk(p0[4], p0[5]),  b1 = cvtpk(p0[6], p0[7]);
      unsigned a2 = cvtpk(p0[8], p0[9]),  a3 = cvtpk(p0[10], p0[11]);
      unsigned b2 = cvtpk(p0[12], p0[13]), b3 = cvtpk(p0[14], p0[15]);
      plswap(a0, b0); plswap(a1, b1); plswap(a2, b2); plswap(a3, b3);
      pa[0] = mk8(a0, a1, b0, b1);
      pa[1] = mk8(a2, a3, b2, b3);
      unsigned c0 = cvtpk(p1[0], p1[1]),  c1 = cvtpk(p1[2], p1[3]);
      unsigned d0 = cvtpk(p1[4], p1[5]),  d1 = cvtpk(p1[6], p1[7]);
      unsigned c2 = cvtpk(p1[8], p1[9]),  c3 = cvtpk(p1[10], p1[11]);
      unsigned d2 = cvtpk(p1[12], p1[13]), d3 = cvtpk(p1[14], p1[15]);
      plswap(c0, d0); plswap(c1, d1); plswap(c2, d2); plswap(c3, d3);
      pa[2] = mk8(c0, c1, d0, d1);
      pa[3] = mk8(c2, c3, d2, d3);
    }

    #pragma unroll
    for (int db = 0; db < 4; db++) {
      const bf16_t* vr = Vb + (32 * db + l31) * 64;
      #pragma unroll
      for (int ks = 0; ks < 4; ks++) {
        bf16x8 vf = *(const bf16x8*)(vr + ((2 * ks + hi) ^ swz) * 8);
        acc[db] = MFMA32(pa[ks], vf, acc[db], 0, 0, 0);
      }
    }
    __builtin_amdgcn_s_barrier();
  }

  size_t obase = ((size_t)(z * NH + h) * S + q0w) * DH;
  #pragma unroll
  for (int r = 0; r < 16; r++) {
    int qr = (r & 3) + 8 * (r >> 2) + 4 * hi;
    #pragma unroll
    for (int db = 0; db < 4; db++)
      OP[obase + (size_t)qr * DH + db * 32 + l31] = (bf16_t)acc[db][r];
  }
  if (hi == 0) ml[(size_t)(z * NH + h) * S + q] = make_float2(m, lsum);
}

// ---------------- lm head ----------------
__global__ __launch_bounds__(256) void wcvt(const float* __restrict__ w, bf16_t* __restrict__ wb) {
  int i = blockIdx.x * 256 + threadIdx.x;
  float4 f = ((const float4*)w)[i];
  bf16x4 v;
  v[0] = (bf16_t)f.x; v[1] = (bf16_t)f.y; v[2] = (bf16_t)f.z; v[3] = (bf16_t)f.w;
  *(bf16x4*)(wb + (size_t)i * 4) = v;
}

__global__ __launch_bounds__(256) void lm_head(const bf16_t* __restrict__ hb,
                                               const bf16_t* __restrict__ wbf,
                                               const float* __restrict__ bias,
                                               float* __restrict__ out) {
  __shared__ float red[4][16][130];
  int tid = threadIdx.x;
  int w = tid >> 6, l = tid & 63, l16 = l & 15, g = l >> 4;
  int t0 = blockIdx.x * 16;
  f32x4 acc[8];
  #pragma unroll
  for (int i = 0; i < 8; i++) acc[i] = (f32x4){0.f, 0.f, 0.f, 0.f};
  const bf16_t* arow = hb + (size_t)(t0 + l16) * HID + w * 512;
  for (int k0 = 0; k0 < 512; k0 += 32) {
    bf16x8 af = *(const bf16x8*)(arow + k0 + g * 8);
    #pragma unroll
    for (int vt = 0; vt < 8; vt++) {
      bf16x8 bf_ = *(const bf16x8*)(wbf + (size_t)(vt * 16 + l16) * HID + w * 512 + k0 + g * 8);
      acc[vt] = MFMA16(af, bf_, acc[vt], 0, 0, 0);
    }
  }
  #pragma unroll
  for (int vt = 0; vt < 8; vt++)
    #pragma unroll
    for (int r = 0; r < 4; r++)
      red[w][4 * g + r][vt * 16 + l16] = acc[vt][r];
  __syncthreads();
  int q = tid >> 4, vc = (tid & 15) * 8;
  #pragma unroll
  for (int j = 0; j < 8; j++) {
    float s = red[0][q][vc + j] + red[1][q][vc + j] + red[2][q][vc + j] + red[3][q][vc + j];
    out[(size_t)(t0 + q) * VOC + vc + j] = s + bias[vc + j];
  }
}

// ---------------- segment head (bf16 hidden) ----------------
__global__ __launch_bounds__(256) void seg_head(const bf16_t* __restrict__ hb,
                                                const float* __restrict__ sw,
                                                const float* __restrict__ sb,
                                                float* __restrict__ out) {
  int tid = threadIdx.x;
  int token = blockIdx.x * 8 + (tid >> 5);
  int lane = tid & 31;
  const bf16x8* hr = (const bf16x8*)(hb + (size_t)token * HID);
  const float4* w0 = (const float4*)sw;
  const float4* w1 = (const float4*)(sw + HID);
  float a0 = 0.f, a1 = 0.f;
  #pragma unroll
  for (int i = 0; i < 8; i++) {
    int c = lane + i * 32;
    bf16x8 v = hr[c];
    float4 x0 = w0[c * 2], x1 = w0[c * 2 + 1];
    float4 y0 = w1[c * 2], y1 = w1[c * 2 + 1];
    a0 += (float)v[0]*x0.x + (float)v[1]*x0.y + (float)v[2]*x0.z + (float)v[3]*x0.w
        + (float)v[4]*x1.x + (float)v[5]*x1.y + (float)v[6]*x1.z + (float)v[7]*x1.w;
    a1 += (float)v[0]*y0.x + (float)v[1]*y0.y + (float)v[2]*y0.z + (float)v[3]*y0.w
        + (float)v[4]*y1.x + (float)v[5]*y1.y + (float)v[6]*y1.z + (float)v[7]*y1.w;
  }
  #pragma unroll
  for (int off = 16; off; off >>= 1) {
    a0 += __shfl_xor(a0, off, 64);
    a1 += __shfl_xor(a1, off, 64);
  }
  if (lane == 0) {
    out[(size_t)token * 2] = a0 + sb[0];
    out[(size_t)token * 2 + 1] = a1 + sb[1];
  }
}

extern "C" void kernel_launch(void* const* d_in, const int* in_sizes, int n_in,
                              void* d_out, int out_size, void* d_ws, size_t ws_size,
                              hipStream_t stream) {
  const int* tokens = (const int*)d_in[0];
  const unsigned char* seg = (const unsigned char*)d_in[1];
  const unsigned char* spc = (const unsigned char*)d_in[2];
  const float* emb_w = (const float*)d_in[3];
  const float* lm_w = (const float*)d_in[4];
  const float* lm_b = (const float*)d_in[5];
  const float* seg_w = (const float*)d_in[6];
  const float* seg_b = (const float*)d_in[7];

  char* ws = (char*)d_ws;
  int4* mi = (int4*)ws;                                  // 32KB  @0
  unsigned* cmask = (unsigned*)(ws + (1u << 20));        // 512KB @1MB
  float2* ml = (float2*)(ws + (2u << 20));               // 768KB @2MB
  int* tilecnt = (int*)(ws + (3u << 20));                // 64B   @3MB
  int* tilelist = (int*)(ws + (3u << 20) + 4096);        // 2KB   @3MB+4K
  bf16_t* wbf = (bf16_t*)(ws + (3u << 20) + (512u << 10)); // 512KB @3.5MB
  bf16_t* hb  = (bf16_t*)(ws + (4u << 20));              // 8MB   @4MB
  bf16_t* hbT = (bf16_t*)(ws + (12u << 20));             // 8MB   @12MB
  bf16_t* OP  = (bf16_t*)(ws + (20u << 20));             // 24MB  @20MB
  float* out = (float*)d_out;

  mask_prep<<<1, 256, 0, stream>>>(tokens, seg, spc, mi);
  bitgen<<<dim3(64, 8), 256, 0, stream>>>(mi, cmask);
  tprep<<<16, 256, 0, stream>>>(cmask, tilecnt, tilelist);
  embedT<<<dim3(S / 64, NH), 256, 0, stream>>>(tokens, emb_w, hb, hbT);

  for (int L = 0; L < 4; L++) {
    attn3<<<dim3(NH, 16, NZ), 256, 0, stream>>>(hb, hbT, cmask, tilecnt, tilelist, OP, ml);
    combine_k<<<dim3(S / 64, NH), 256, 0, stream>>>(OP, ml, tilecnt, hb, hbT);
  }

  wcvt<<<(VOC * HID / 4) / 256, 256, 0, stream>>>(lm_w, wbf);
  lm_head<<<S / 16, 256, 0, stream>>>(hb, wbf, lm_b, out);
  seg_head<<<S / 8, 256, 0, stream>>>(hb, seg_w, seg_b, out + (size_t)S * VOC);
}

// Round 7
// 154.809 us; speedup vs baseline: 2.7227x; 1.3641x over previous
//
#include <hip/hip_runtime.h>

#define S 2048
#define HID 2048
#define NH 16
#define DH 128
#define VOC 128
#define LCAP 128
#define K2EXP 0.12752551286084112f   // (1/sqrt(128)) * log2(e)
#define RTHR 62.0f                   // defer-max threshold in raw-score units
#define NEGS -3.0e38f

typedef __bf16 bf16_t;
typedef __attribute__((ext_vector_type(8))) __bf16 bf16x8;
typedef __attribute__((ext_vector_type(4))) __bf16 bf16x4;
typedef __attribute__((ext_vector_type(4))) float f32x4;
typedef __attribute__((ext_vector_type(16))) float f32x16;

typedef __attribute__((address_space(1))) unsigned int guint;
typedef __attribute__((address_space(3))) unsigned int luint;

#define MFMA16 __builtin_amdgcn_mfma_f32_16x16x32_bf16
#define MFMA32 __builtin_amdgcn_mfma_f32_32x32x16_bf16

__device__ __forceinline__ void gl_lds16(const void* g, void* l) {
  __builtin_amdgcn_global_load_lds((guint*)(unsigned long long)g,
                                   (luint*)(unsigned)(unsigned long long)l,
                                   16, 0, 0);
}

__device__ __forceinline__ unsigned cvtpk(float lo, float hi) {
  unsigned r;
  asm("v_cvt_pk_bf16_f32 %0, %1, %2" : "=v"(r) : "v"(lo), "v"(hi));
  return r;
}
__device__ __forceinline__ void plswap(unsigned& a, unsigned& b) {
  asm volatile("v_permlane32_swap_b32 %0, %1" : "+v"(a), "+v"(b));
}
__device__ __forceinline__ bf16x8 mk8(unsigned d0, unsigned d1, unsigned d2, unsigned d3) {
  union { unsigned u[4]; bf16x8 v; } x;
  x.u[0] = d0; x.u[1] = d1; x.u[2] = d2; x.u[3] = d3;
  return x.v;
}

// ---------------- mask precompute: intervals + starts + landmarks + stripe meta ----------------
__global__ __launch_bounds__(256) void maskprep2(const int* __restrict__ tokens,
                                                 const unsigned char* __restrict__ seg,
                                                 const unsigned char* __restrict__ spc,
                                                 int4* __restrict__ mi,
                                                 int* __restrict__ kvL,
                                                 int2* __restrict__ smeta) {
  __shared__ int ssp[257], ssg[257], smw[257], sms[257], sfl[257];
  __shared__ int fpre[2048];
  __shared__ int ns16[16];
  __shared__ int cdet[2];
  int t = threadIdx.x;
  if (t < 2) cdet[t] = 0;
  __syncthreads();
  {
    int nz = ((t & 3) != 0 && seg[t]) ? 1 : 0;
    int fc = ((t & 3) == 3 && seg[t] == 0x3f) ? 1 : 0;
    if (nz) atomicAdd(&cdet[0], 1);
    if (fc) atomicAdd(&cdet[1], 1);
  }
  __syncthreads();
  int lay = (cdet[1] > 8) ? 2 : ((cdet[0] > 4) ? 1 : 0);
  auto getb = [&](const unsigned char* p, int i) -> int {
    if (lay == 1) return p[i] != 0;
    if (lay == 2) return ((const float*)p)[i] != 0.f;
    return ((const int*)p)[i] != 0;
  };
  int base = t * 8;
  int spv[8], sgv[8], npv[8], fv[8];
  int a = 0, b = 0, mw = 0, ms = 0, fs = 0;
  for (int j = 0; j < 8; j++) {
    int i = base + j;
    spv[j] = getb(spc, i);
    sgv[j] = 1 - getb(seg, i);
    npv[j] = (tokens[i] != 127) ? 1 : 0;
    fv[j] = spv[j] & sgv[j] & npv[j];
    a += spv[j]; b += sgv[j]; fs += fv[j];
    if (i >= 1 && spv[j]) mw = (i + 1 > mw) ? i + 1 : mw;
    if (i >= 1 && sgv[j]) ms = (i + 1 > ms) ? i + 1 : ms;
  }
  ssp[t + 1] = a; ssg[t + 1] = b; smw[t + 1] = mw; sms[t + 1] = ms; sfl[t + 1] = fs;
  if (t == 0) { ssp[0] = 0; ssg[0] = 0; smw[0] = 0; sms[0] = 0; sfl[0] = 0; }
  __syncthreads();
  for (int off = 1; off < 256; off <<= 1) {
    int v0 = 0, v1 = 0, v2 = 0, v3 = 0, v4 = 0;
    if (t + 1 > off) { v0 = ssp[t+1-off]; v1 = ssg[t+1-off]; v2 = smw[t+1-off]; v3 = sms[t+1-off]; v4 = sfl[t+1-off]; }
    __syncthreads();
    ssp[t + 1] += v0; ssg[t + 1] += v1;
    if (v2 > smw[t + 1]) smw[t + 1] = v2;
    if (v3 > sms[t + 1]) sms[t + 1] = v3;
    sfl[t + 1] += v4;
    __syncthreads();
  }
  // per-stripe near-start (exclusive prefix-max at element 128*st = thread base of t=16*st)
  if ((t & 15) == 0) {
    int ws = smw[t], ss = sms[t];
    ns16[t >> 4] = ws < ss ? ws : ss;
  }
  int nL = sfl[256];
  // zero-pad kvL beyond nL (disjoint from scatter positions)
  if (t < LCAP && t >= nL) kvL[t] = 0;
  int esp = ssp[t], esg = ssg[t], ef = sfl[t];
  for (int j = 0; j < 8; j++) {
    int i = base + j;
    int wint = (i == 0) ? (1 + spv[j]) : (1 + esp);
    int sint = (i == 0) ? (1 + sgv[j]) : (1 + esg);
    mi[i] = make_int4(npv[j] | (spv[j] << 1) | (sgv[j] << 2), wint, sint, 0);
    fpre[i] = ef;
    if (fv[j] && ef < LCAP) kvL[ef] = i;
    esp += spv[j]; esg += sgv[j]; ef += fv[j];
  }
  __syncthreads();
  if (t < 16) {
    int nsT = ns16[t] >> 6;
    int lc = fpre[nsT * 64];              // fpre[0]==0
    if (lc > LCAP) lc = LCAP;
    smeta[t] = make_int2(nsT, lc);
  }
}

// ---------------- full mask bit table: cmask[word][q], word=kv/32 ----------------
__global__ __launch_bounds__(256) void bitgen(const int4* __restrict__ mi,
                                              unsigned* __restrict__ cmask) {
  __shared__ int4 km[32];
  int w = blockIdx.x;
  int t = threadIdx.x;
  int q = blockIdx.y * 256 + t;
  if (t < 32) km[t] = mi[w * 32 + t];
  __syncthreads();
  int4 mq = mi[q];
  unsigned word = 0;
  #pragma unroll
  for (int j = 0; j < 32; j++) {
    int kv = w * 32 + j;
    int4 mk = km[j];
    bool v = ((mq.x & mk.x) & 1) &&
             ((mk.x & 2) || (mq.y == mk.y)) &&
             ((mk.x & 4) || (mq.z == mk.z)) &&
             (kv <= q);
    word |= (v ? 1u : 0u) << j;
  }
  cmask[(size_t)w * S + q] = word;
}

// ---------------- gather landmark K rows + transposed copy ----------------
__global__ __launch_bounds__(256) void gatherLT(const bf16_t* __restrict__ hb,
                                                const int* __restrict__ kvL,
                                                bf16_t* __restrict__ hbL,
                                                bf16_t* __restrict__ hbLT) {
  __shared__ bf16_t tl[128][72];
  int dt = blockIdx.x;              // d-chunk 0..31 (64 cols)
  int tid = threadIdx.x;
  int jr = tid >> 1, c32 = (tid & 1) * 32;
  int kv = kvL[jr];
  const bf16_t* src = hb + (size_t)kv * HID + dt * 64 + c32;
  bf16_t* dstL = hbL + (size_t)jr * HID + dt * 64 + c32;
  #pragma unroll
  for (int k = 0; k < 4; k++) {
    bf16x8 v = *(const bf16x8*)(src + k * 8);
    *(bf16x8*)(dstL + k * 8) = v;
    #pragma unroll
    for (int e = 0; e < 8; e++) tl[jr][c32 + k * 8 + e] = v[e];
  }
  __syncthreads();
  int dr = tid >> 2, jq = (tid & 3) * 32;
  bf16_t* dstT = hbLT + (size_t)(dt * 64 + dr) * LCAP + jq;
  #pragma unroll
  for (int k = 0; k < 4; k++) {
    bf16x8 v;
    #pragma unroll
    for (int e = 0; e < 8; e++) v[e] = tl[jq + k * 8 + e][dr];
    *(bf16x8*)(dstT + k * 8) = v;
  }
}

// ---------------- shared transpose-store helper (embed) ----------------
__device__ __forceinline__ void store_h_hT(bf16x8 ob[4], bf16_t* tile, int q0, int h,
                                           int ql, int d0, int tid,
                                           bf16_t* __restrict__ hb, bf16_t* __restrict__ hbT) {
  #pragma unroll
  for (int i = 0; i < 4; i++)
    *(bf16x8*)(hb + (size_t)(q0 + ql) * HID + h * DH + d0 + i * 8) = ob[i];
  #pragma unroll
  for (int i = 0; i < 4; i++)
    #pragma unroll
    for (int j = 0; j < 8; j++) tile[ql * 136 + d0 + i * 8 + j] = ob[i][j];
  __syncthreads();
  int dT = tid >> 1, qh = (tid & 1) * 32;
  bf16x8 tb[4];
  #pragma unroll
  for (int i = 0; i < 4; i++)
    #pragma unroll
    for (int j = 0; j < 8; j++) tb[i][j] = tile[(qh + i * 8 + j) * 136 + dT];
  #pragma unroll
  for (int i = 0; i < 4; i++)
    *(bf16x8*)(hbT + (size_t)(h * DH + dT) * S + q0 + qh + i * 8) = tb[i];
}

// ---------------- embedding gather -> bf16 h and h^T ----------------
__global__ __launch_bounds__(256) void embedT(const int* __restrict__ tokens,
                                              const float* __restrict__ emb,
                                              bf16_t* __restrict__ hb, bf16_t* __restrict__ hbT) {
  __shared__ bf16_t tile[64 * 136];
  int tid = threadIdx.x;
  int q0 = blockIdx.x * 64, h = blockIdx.y;
  int ql = tid >> 2, d0 = (tid & 3) * 32;
  int tok = tokens[q0 + ql];
  const float4* src = (const float4*)(emb + (size_t)tok * HID + h * DH + d0);
  bf16x8 ob[4];
  #pragma unroll
  for (int i = 0; i < 8; i++) {
    float4 f = src[i];
    ob[i >> 1][(i & 1) * 4 + 0] = (bf16_t)f.x;
    ob[i >> 1][(i & 1) * 4 + 1] = (bf16_t)f.y;
    ob[i >> 1][(i & 1) * 4 + 2] = (bf16_t)f.z;
    ob[i >> 1][(i & 1) * 4 + 3] = (bf16_t)f.w;
  }
  store_h_hT(ob, tile, q0, h, ql, d0, tid, hb, hbT);
}

// ---------------- fused attention layer: near tiles + landmark tiles ----------------
__global__ __launch_bounds__(256, 2) void attn4(const bf16_t* __restrict__ hb,
                                                const bf16_t* __restrict__ hbT,
                                                const bf16_t* __restrict__ hbL,
                                                const bf16_t* __restrict__ hbLT,
                                                const unsigned* __restrict__ cmask,
                                                const int4* __restrict__ mi,
                                                const int2* __restrict__ smeta,
                                                bf16_t* __restrict__ ob,
                                                bf16_t* __restrict__ obT,
                                                int writeT) {
  __shared__ __align__(16) char lds_raw[65536];

  int h = blockIdx.x, st = blockIdx.y;
  int2 sm = smeta[st];
  int nsT = sm.x, lcount = sm.y;
  int nNear = 2 * st + 2 - nsT;
  int nLT = (lcount + 63) >> 6;
  int nIter = nNear + nLT;

  int tid = threadIdx.x, w = tid >> 6, l = tid & 63, l31 = l & 31, hi = l >> 5;
  int q0w = 128 * st + 32 * w, q = q0w + l31;
  int npq = mi[q].x & 1;

  bf16x8 qf[8];
  {
    const bf16_t* hq = hb + (size_t)q * HID + h * DH;
    #pragma unroll
    for (int ks = 0; ks < 8; ks++) qf[ks] = *(const bf16x8*)(hq + ks * 16 + hi * 8);
  }

  f32x16 acc[4];
  #pragma unroll
  for (int i = 0; i < 4; i++)
    #pragma unroll
    for (int r = 0; r < 16; r++) acc[i][r] = 0.f;
  float m = -1e30f, lsum = 0.f;
  int swz = l31 & 7;

  auto STAGE = [&](int i, int b) {
    const bf16_t* Kbase; const bf16_t* Vbase; size_t Vstr;
    if (i < nNear) {
      int kv0 = (nsT + i) * 64;
      Kbase = hb + (size_t)kv0 * HID + h * DH;
      Vbase = hbT + (size_t)(h * DH) * S + kv0; Vstr = S;
    } else {
      int j0 = (i - nNear) * 64;
      Kbase = hbL + (size_t)j0 * HID + h * DH;
      Vbase = hbLT + (size_t)(h * DH) * LCAP + j0; Vstr = LCAP;
    }
    bf16_t* Kb = (bf16_t*)(lds_raw + b * 16384);
    bf16_t* Vb = (bf16_t*)(lds_raw + 32768 + b * 16384);
    #pragma unroll
    for (int i2 = 0; i2 < 4; i2++) {
      int sg = w * 4 + i2;
      int rowK = sg * 4 + (l >> 4); int chK = (l & 15) ^ (rowK & 7);
      gl_lds16(Kbase + (size_t)rowK * HID + chK * 8, Kb + sg * 512);
      int rowV = sg * 8 + (l >> 3); int chV = (l & 7) ^ (rowV & 7);
      gl_lds16(Vbase + (size_t)rowV * Vstr + chV * 8, Vb + sg * 512);
    }
  };

  auto getmask = [&](int i, unsigned& w0, unsigned& w1) {
    if (i < nNear) {
      int tt = nsT + i;
      w0 = cmask[(size_t)(2 * tt) * S + q];
      w1 = cmask[(size_t)(2 * tt + 1) * S + q];
    } else {
      int rem = lcount - (i - nNear) * 64;
      w0 = (rem >= 32) ? 0xffffffffu : ((rem <= 0) ? 0u : ((1u << rem) - 1u));
      int r2 = rem - 32;
      w1 = (r2 >= 32) ? 0xffffffffu : ((r2 <= 0) ? 0u : ((1u << r2) - 1u));
      if (!npq) { w0 = 0u; w1 = 0u; }
    }
  };

  STAGE(0, 0);
  for (int i = 0; i < nIter; i++) {
    int b = i & 1;
    unsigned w0, w1;
    getmask(i, w0, w1);
    if (i + 1 < nIter) {
      STAGE(i + 1, b ^ 1);
      asm volatile("s_waitcnt vmcnt(8)" ::: "memory");
    } else {
      asm volatile("s_waitcnt vmcnt(0)" ::: "memory");
    }
    __builtin_amdgcn_s_barrier();
    __builtin_amdgcn_sched_barrier(0);

    if (__any((w0 | w1) != 0u)) {
      const bf16_t* Kb = (const bf16_t*)(lds_raw + b * 16384);
      const bf16_t* Vb = (const bf16_t*)(lds_raw + 32768 + b * 16384);
      f32x16 s0, s1;
      #pragma unroll
      for (int r = 0; r < 16; r++) { s0[r] = 0.f; s1[r] = 0.f; }
      const bf16_t* k0p = Kb + l31 * 128;
      const bf16_t* k1p = Kb + (32 + l31) * 128;
      #pragma unroll
      for (int ks = 0; ks < 8; ks++) {
        int ch = ((2 * ks + hi) ^ swz) * 8;
        bf16x8 kf0 = *(const bf16x8*)(k0p + ch);
        bf16x8 kf1 = *(const bf16x8*)(k1p + ch);
        s0 = MFMA32(kf0, qf[ks], s0, 0, 0, 0);
        s1 = MFMA32(kf1, qf[ks], s1, 0, 0, 0);
      }

      float sv0[16], sv1[16];
      float mx = NEGS;
      #pragma unroll
      for (int r = 0; r < 16; r++) {
        int bit = (r & 3) + 8 * (r >> 2) + 4 * hi;
        sv0[r] = ((w0 >> bit) & 1u) ? s0[r] : NEGS;
        sv1[r] = ((w1 >> bit) & 1u) ? s1[r] : NEGS;
        mx = fmaxf(mx, fmaxf(sv0[r], sv1[r]));
      }
      mx = fmaxf(mx, __shfl_xor(mx, 32, 64));
      if (__any(mx > m + RTHR)) {
        float mn = fmaxf(m, mx);
        float al = exp2f((m - mn) * K2EXP);
        m = mn; lsum *= al;
        #pragma unroll
        for (int r = 0; r < 16; r++) {
          float alr = __shfl(al, (r & 3) + 8 * (r >> 2) + 4 * hi, 64);
          #pragma unroll
          for (int d = 0; d < 4; d++) acc[d][r] *= alr;
        }
      }
      float mk = m * K2EXP;
      float p0[16], p1[16], ps = 0.f;
      #pragma unroll
      for (int r = 0; r < 16; r++) {
        p0[r] = exp2f(__builtin_fmaf(sv0[r], K2EXP, -mk));
        p1[r] = exp2f(__builtin_fmaf(sv1[r], K2EXP, -mk));
        ps += p0[r] + p1[r];
      }
      ps += __shfl_xor(ps, 32, 64);
      lsum += ps;

      bf16x8 pa[4];
      {
        unsigned a0 = cvtpk(p0[0], p0[1]),  a1 = cvtpk(p0[2], p0[3]);
        unsigned b0 = cvtpk(p0[4], p0[5]),  b1 = cvtpk(p0[6], p0[7]);
        unsigned a2 = cvtpk(p0[8], p0[9]),  a3 = cvtpk(p0[10], p0[11]);
        unsigned b2 = cvtpk(p0[12], p0[13]), b3 = cvtpk(p0[14], p0[15]);
        plswap(a0, b0); plswap(a1, b1); plswap(a2, b2); plswap(a3, b3);
        pa[0] = mk8(a0, a1, b0, b1);
        pa[1] = mk8(a2, a3, b2, b3);
        unsigned c0 = cvtpk(p1[0], p1[1]),  c1 = cvtpk(p1[2], p1[3]);
        unsigned d0 = cvtpk(p1[4], p1[5]),  d1 = cvtpk(p1[6], p1[7]);
        unsigned c2 = cvtpk(p1[8], p1[9]),  c3 = cvtpk(p1[10], p1[11]);
        unsigned d2 = cvtpk(p1[12], p1[13]), d3 = cvtpk(p1[14], p1[15]);
        plswap(c0, d0); plswap(c1, d1); plswap(c2, d2); plswap(c3, d3);
        pa[2] = mk8(c0, c1, d0, d1);
        pa[3] = mk8(c2, c3, d2, d3);
      }

      #pragma unroll
      for (int db = 0; db < 4; db++) {
        const bf16_t* vr = Vb + (32 * db + l31) * 64;
        #pragma unroll
        for (int ks = 0; ks < 4; ks++) {
          bf16x8 vf = *(const bf16x8*)(vr + ((2 * ks + hi) ^ swz) * 8);
          acc[db] = MFMA32(pa[ks], vf, acc[db], 0, 0, 0);
        }
      }
    }
    __builtin_amdgcn_s_barrier();
  }

  // epilogue: normalize, write hb and hbT (reuse LDS)
  __syncthreads();
  bf16_t* tl = (bf16_t*)lds_raw + w * (32 * 132);
  float inv = (lsum > 0.f) ? 1.f / lsum : 0.f;
  #pragma unroll
  for (int r = 0; r < 16; r++) {
    int qr = (r & 3) + 8 * (r >> 2) + 4 * hi;
    float ivr = __shfl(inv, qr, 64);
    #pragma unroll
    for (int db = 0; db < 4; db++)
      tl[qr * 132 + db * 32 + l31] = (bf16_t)(acc[db][r] * ivr);
  }
  asm volatile("s_waitcnt lgkmcnt(0)" ::: "memory");
  __builtin_amdgcn_sched_barrier(0);
  {
    int qr2 = l >> 1;
    #pragma unroll
    for (int k = 0; k < 8; k++) {
      int ch = (l & 1) * 8 + k;
      bf16x8 v = *(const bf16x8*)(tl + qr2 * 132 + ch * 8);
      *(bf16x8*)(ob + (size_t)(q0w + qr2) * HID + h * DH + ch * 8) = v;
    }
  }
  if (writeT) {
    #pragma unroll
    for (int j = 0; j < 2; j++) {
      int dd = l + 64 * j;
      #pragma unroll
      for (int c = 0; c < 4; c++) {
        bf16x8 v;
        #pragma unroll
        for (int k = 0; k < 8; k++) v[k] = tl[(c * 8 + k) * 132 + dd];
        *(bf16x8*)(obT + (size_t)(h * DH + dd) * S + q0w + c * 8) = v;
      }
    }
  }
}

// ---------------- lm head ----------------
__global__ __launch_bounds__(256) void wcvt(const float* __restrict__ w, bf16_t* __restrict__ wb) {
  int i = blockIdx.x * 256 + threadIdx.x;
  float4 f = ((const float4*)w)[i];
  bf16x4 v;
  v[0] = (bf16_t)f.x; v[1] = (bf16_t)f.y; v[2] = (bf16_t)f.z; v[3] = (bf16_t)f.w;
  *(bf16x4*)(wb + (size_t)i * 4) = v;
}

__global__ __launch_bounds__(256) void lm_head(const bf16_t* __restrict__ hb,
                                               const bf16_t* __restrict__ wbf,
                                               const float* __restrict__ bias,
                                               float* __restrict__ out) {
  __shared__ float red[4][16][130];
  int tid = threadIdx.x;
  int w = tid >> 6, l = tid & 63, l16 = l & 15, g = l >> 4;
  int t0 = blockIdx.x * 16;
  f32x4 acc[8];
  #pragma unroll
  for (int i = 0; i < 8; i++) acc[i] = (f32x4){0.f, 0.f, 0.f, 0.f};
  const bf16_t* arow = hb + (size_t)(t0 + l16) * HID + w * 512;
  for (int k0 = 0; k0 < 512; k0 += 32) {
    bf16x8 af = *(const bf16x8*)(arow + k0 + g * 8);
    #pragma unroll
    for (int vt = 0; vt < 8; vt++) {
      bf16x8 bf_ = *(const bf16x8*)(wbf + (size_t)(vt * 16 + l16) * HID + w * 512 + k0 + g * 8);
      acc[vt] = MFMA16(af, bf_, acc[vt], 0, 0, 0);
    }
  }
  #pragma unroll
  for (int vt = 0; vt < 8; vt++)
    #pragma unroll
    for (int r = 0; r < 4; r++)
      red[w][4 * g + r][vt * 16 + l16] = acc[vt][r];
  __syncthreads();
  int q = tid >> 4, vc = (tid & 15) * 8;
  #pragma unroll
  for (int j = 0; j < 8; j++) {
    float s = red[0][q][vc + j] + red[1][q][vc + j] + red[2][q][vc + j] + red[3][q][vc + j];
    out[(size_t)(t0 + q) * VOC + vc + j] = s + bias[vc + j];
  }
}

// ---------------- segment head (bf16 hidden) ----------------
__global__ __launch_bounds__(256) void seg_head(const bf16_t* __restrict__ hb,
                                                const float* __restrict__ sw,
                                                const float* __restrict__ sb,
                                                float* __restrict__ out) {
  int tid = threadIdx.x;
  int token = blockIdx.x * 8 + (tid >> 5);
  int lane = tid & 31;
  const bf16x8* hr = (const bf16x8*)(hb + (size_t)token * HID);
  const float4* w0 = (const float4*)sw;
  const float4* w1 = (const float4*)(sw + HID);
  float a0 = 0.f, a1 = 0.f;
  #pragma unroll
  for (int i = 0; i < 8; i++) {
    int c = lane + i * 32;
    bf16x8 v = hr[c];
    float4 x0 = w0[c * 2], x1 = w0[c * 2 + 1];
    float4 y0 = w1[c * 2], y1 = w1[c * 2 + 1];
    a0 += (float)v[0]*x0.x + (float)v[1]*x0.y + (float)v[2]*x0.z + (float)v[3]*x0.w
        + (float)v[4]*x1.x + (float)v[5]*x1.y + (float)v[6]*x1.z + (float)v[7]*x1.w;
    a1 += (float)v[0]*y0.x + (float)v[1]*y0.y + (float)v[2]*y0.z + (float)v[3]*y0.w
        + (float)v[4]*y1.x + (float)v[5]*y1.y + (float)v[6]*y1.z + (float)v[7]*y1.w;
  }
  #pragma unroll
  for (int off = 16; off; off >>= 1) {
    a0 += __shfl_xor(a0, off, 64);
    a1 += __shfl_xor(a1, off, 64);
  }
  if (lane == 0) {
    out[(size_t)token * 2] = a0 + sb[0];
    out[(size_t)token * 2 + 1] = a1 + sb[1];
  }
}

extern "C" void kernel_launch(void* const* d_in, const int* in_sizes, int n_in,
                              void* d_out, int out_size, void* d_ws, size_t ws_size,
                              hipStream_t stream) {
  const int* tokens = (const int*)d_in[0];
  const unsigned char* seg = (const unsigned char*)d_in[1];
  const unsigned char* spc = (const unsigned char*)d_in[2];
  const float* emb_w = (const float*)d_in[3];
  const float* lm_w = (const float*)d_in[4];
  const float* lm_b = (const float*)d_in[5];
  const float* seg_w = (const float*)d_in[6];
  const float* seg_b = (const float*)d_in[7];

  char* ws = (char*)d_ws;
  int4* mi = (int4*)ws;                                   // 32KB  @0
  unsigned* cmask = (unsigned*)(ws + (1u << 20));         // 512KB @1MB
  int* kvL = (int*)(ws + (1u << 20) + (512u << 10));      // 512B
  int2* smeta = (int2*)(ws + (1u << 20) + (513u << 10));  // 128B
  bf16_t* hbL  = (bf16_t*)(ws + (2u << 20));              // 512KB @2MB
  bf16_t* hbLT = (bf16_t*)(ws + (2u << 20) + (512u << 10)); // 512KB @2.5MB
  bf16_t* wbf  = (bf16_t*)(ws + (3u << 20));              // 512KB @3MB
  bf16_t* hbA  = (bf16_t*)(ws + (4u << 20));              // 8MB   @4MB
  bf16_t* hbTA = (bf16_t*)(ws + (12u << 20));             // 8MB   @12MB
  bf16_t* hbB  = (bf16_t*)(ws + (20u << 20));             // 8MB   @20MB
  bf16_t* hbTB = (bf16_t*)(ws + (28u << 20));             // 8MB   @28MB
  float* out = (float*)d_out;

  maskprep2<<<1, 256, 0, stream>>>(tokens, seg, spc, mi, kvL, smeta);
  bitgen<<<dim3(64, 8), 256, 0, stream>>>(mi, cmask);
  embedT<<<dim3(S / 64, NH), 256, 0, stream>>>(tokens, emb_w, hbA, hbTA);

  bf16_t* cur = hbA;  bf16_t* curT = hbTA;
  bf16_t* nxt = hbB;  bf16_t* nxtT = hbTB;
  for (int L = 0; L < 4; L++) {
    gatherLT<<<32, 256, 0, stream>>>(cur, kvL, hbL, hbLT);
    attn4<<<dim3(NH, 16), 256, 0, stream>>>(cur, curT, hbL, hbLT, cmask, mi, smeta,
                                            nxt, nxtT, (L < 3) ? 1 : 0);
    bf16_t* t1 = cur; cur = nxt; nxt = t1;
    bf16_t* t2 = curT; curT = nxtT; nxtT = t2;
  }

  wcvt<<<(VOC * HID / 4) / 256, 256, 0, stream>>>(lm_w, wbf);
  lm_head<<<S / 16, 256, 0, stream>>>(cur, wbf, lm_b, out);
  seg_head<<<S / 8, 256, 0, stream>>>(cur, seg_w, seg_b, out + (size_t)S * VOC);
}

// Round 8
// 143.772 us; speedup vs baseline: 2.9317x; 1.0768x over previous
//
#include <hip/hip_runtime.h>

#define S 2048
#define HID 2048
#define NH 16
#define DH 128
#define VOC 128
#define LCAP 128
#define K2EXP 0.12752551286084112f   // (1/sqrt(128)) * log2(e)
#define RTHR 62.0f                   // defer-max threshold in raw-score units
#define NEGS -3.0e38f

typedef __bf16 bf16_t;
typedef __attribute__((ext_vector_type(8))) __bf16 bf16x8;
typedef __attribute__((ext_vector_type(4))) __bf16 bf16x4;
typedef __attribute__((ext_vector_type(4))) float f32x4;
typedef __attribute__((ext_vector_type(16))) float f32x16;

typedef __attribute__((address_space(1))) unsigned int guint;
typedef __attribute__((address_space(3))) unsigned int luint;

#define MFMA16 __builtin_amdgcn_mfma_f32_16x16x32_bf16
#define MFMA32 __builtin_amdgcn_mfma_f32_32x32x16_bf16

__device__ __forceinline__ void gl_lds16(const void* g, void* l) {
  __builtin_amdgcn_global_load_lds((guint*)(unsigned long long)g,
                                   (luint*)(unsigned)(unsigned long long)l,
                                   16, 0, 0);
}

__device__ __forceinline__ unsigned cvtpk(float lo, float hi) {
  unsigned r;
  asm("v_cvt_pk_bf16_f32 %0, %1, %2" : "=v"(r) : "v"(lo), "v"(hi));
  return r;
}
__device__ __forceinline__ void plswap(unsigned& a, unsigned& b) {
  asm volatile("v_permlane32_swap_b32 %0, %1" : "+v"(a), "+v"(b));
}
__device__ __forceinline__ bf16x8 mk8(unsigned d0, unsigned d1, unsigned d2, unsigned d3) {
  union { unsigned u[4]; bf16x8 v; } x;
  x.u[0] = d0; x.u[1] = d1; x.u[2] = d2; x.u[3] = d3;
  return x.v;
}

// ---------------- mask precompute: intervals + starts + landmarks + stripe meta ----------------
__global__ __launch_bounds__(256) void maskprep2(const int* __restrict__ tokens,
                                                 const unsigned char* __restrict__ seg,
                                                 const unsigned char* __restrict__ spc,
                                                 int4* __restrict__ mi,
                                                 int* __restrict__ lq,
                                                 unsigned long long* __restrict__ lmask,
                                                 int2* __restrict__ smeta) {
  __shared__ int ssp[257], ssg[257], smw[257], sms[257], sfl[257];
  __shared__ int fpre[2048];
  __shared__ int ns32[32];
  __shared__ unsigned long long lmk[32];
  __shared__ int cdet[2];
  int t = threadIdx.x;
  if (t < 2) cdet[t] = 0;
  if (t < 32) lmk[t] = 0ull;
  __syncthreads();
  {
    int nz = ((t & 3) != 0 && seg[t]) ? 1 : 0;
    int fc = ((t & 3) == 3 && seg[t] == 0x3f) ? 1 : 0;
    if (nz) atomicAdd(&cdet[0], 1);
    if (fc) atomicAdd(&cdet[1], 1);
  }
  __syncthreads();
  int lay = (cdet[1] > 8) ? 2 : ((cdet[0] > 4) ? 1 : 0);
  auto getb = [&](const unsigned char* p, int i) -> int {
    if (lay == 1) return p[i] != 0;
    if (lay == 2) return ((const float*)p)[i] != 0.f;
    return ((const int*)p)[i] != 0;
  };
  int base = t * 8;
  int spv[8], sgv[8], npv[8], fv[8];
  int a = 0, b = 0, mw = 0, ms = 0, fs = 0;
  for (int j = 0; j < 8; j++) {
    int i = base + j;
    spv[j] = getb(spc, i);
    sgv[j] = 1 - getb(seg, i);
    npv[j] = (tokens[i] != 127) ? 1 : 0;
    fv[j] = spv[j] & sgv[j] & npv[j];
    a += spv[j]; b += sgv[j]; fs += fv[j];
    if (i >= 1 && spv[j]) mw = (i + 1 > mw) ? i + 1 : mw;
    if (i >= 1 && sgv[j]) ms = (i + 1 > ms) ? i + 1 : ms;
  }
  ssp[t + 1] = a; ssg[t + 1] = b; smw[t + 1] = mw; sms[t + 1] = ms; sfl[t + 1] = fs;
  if (t == 0) { ssp[0] = 0; ssg[0] = 0; smw[0] = 0; sms[0] = 0; sfl[0] = 0; }
  __syncthreads();
  for (int off = 1; off < 256; off <<= 1) {
    int v0 = 0, v1 = 0, v2 = 0, v3 = 0, v4 = 0;
    if (t + 1 > off) { v0 = ssp[t+1-off]; v1 = ssg[t+1-off]; v2 = smw[t+1-off]; v3 = sms[t+1-off]; v4 = sfl[t+1-off]; }
    __syncthreads();
    ssp[t + 1] += v0; ssg[t + 1] += v1;
    if (v2 > smw[t + 1]) smw[t + 1] = v2;
    if (v3 > sms[t + 1]) sms[t + 1] = v3;
    sfl[t + 1] += v4;
    __syncthreads();
  }
  // per-64-stripe near-start (exclusive prefix over [0, 64*st) at t = 8*st)
  if ((t & 7) == 0) {
    int ws = smw[t], ss = sms[t];
    ns32[t >> 3] = ws < ss ? ws : ss;
  }
  int esp = ssp[t], esg = ssg[t], ef = sfl[t];
  for (int j = 0; j < 8; j++) {
    int i = base + j;
    int wint = (i == 0) ? (1 + spv[j]) : (1 + esp);
    int sint = (i == 0) ? (1 + sgv[j]) : (1 + esg);
    mi[i] = make_int4(npv[j] | (spv[j] << 1) | (sgv[j] << 2), wint, sint, 0);
    fpre[i] = ef;
    int lqv = (fv[j] && ef < LCAP) ? ef : -1;
    lq[i] = lqv;
    if (lqv >= 0) atomicOr(&lmk[i >> 6], 1ull << (i & 63));
    esp += spv[j]; esg += sgv[j]; ef += fv[j];
  }
  __syncthreads();
  if (t < 32) {
    lmask[t] = lmk[t];
    int nsTile = ns32[t] >> 6;
    int lc = fpre[nsTile * 64];          // fpre[0]==0
    if (lc > LCAP) lc = LCAP;
    smeta[t] = make_int2(nsTile, lc);
  }
}

// ---------------- full mask bit table: cmask[word][q], word=kv/32 ----------------
__global__ __launch_bounds__(256) void bitgen(const int4* __restrict__ mi,
                                              unsigned* __restrict__ cmask) {
  __shared__ int4 km[32];
  int w = blockIdx.x;
  int t = threadIdx.x;
  int q = blockIdx.y * 256 + t;
  if (t < 32) km[t] = mi[w * 32 + t];
  __syncthreads();
  int4 mq = mi[q];
  unsigned word = 0;
  #pragma unroll
  for (int j = 0; j < 32; j++) {
    int kv = w * 32 + j;
    int4 mk = km[j];
    bool v = ((mq.x & mk.x) & 1) &&
             ((mk.x & 2) || (mq.y == mk.y)) &&
             ((mk.x & 4) || (mq.z == mk.z)) &&
             (kv <= q);
    word |= (v ? 1u : 0u) << j;
  }
  cmask[(size_t)w * S + q] = word;
}

// ---------------- shared transpose-store helper (embed) ----------------
__device__ __forceinline__ void store_h_hT(bf16x8 ob[4], bf16_t* tile, int q0, int h,
                                           int ql, int d0, int tid,
                                           bf16_t* __restrict__ hb, bf16_t* __restrict__ hbT) {
  #pragma unroll
  for (int i = 0; i < 4; i++)
    *(bf16x8*)(hb + (size_t)(q0 + ql) * HID + h * DH + d0 + i * 8) = ob[i];
  #pragma unroll
  for (int i = 0; i < 4; i++)
    #pragma unroll
    for (int j = 0; j < 8; j++) tile[ql * 136 + d0 + i * 8 + j] = ob[i][j];
  __syncthreads();
  int dT = tid >> 1, qh = (tid & 1) * 32;
  bf16x8 tb[4];
  #pragma unroll
  for (int i = 0; i < 4; i++)
    #pragma unroll
    for (int j = 0; j < 8; j++) tb[i][j] = tile[(qh + i * 8 + j) * 136 + dT];
  #pragma unroll
  for (int i = 0; i < 4; i++)
    *(bf16x8*)(hbT + (size_t)(h * DH + dT) * S + q0 + qh + i * 8) = tb[i];
}

// ---------------- embedding gather -> bf16 h, h^T, and landmark copies ----------------
__global__ __launch_bounds__(256) void embedT(const int* __restrict__ tokens,
                                              const float* __restrict__ emb,
                                              const int* __restrict__ lq,
                                              const unsigned long long* __restrict__ lmask,
                                              bf16_t* __restrict__ hb, bf16_t* __restrict__ hbT,
                                              bf16_t* __restrict__ hbL, bf16_t* __restrict__ hbLT) {
  __shared__ bf16_t tile[64 * 136];
  int tid = threadIdx.x;
  int q0 = blockIdx.x * 64, h = blockIdx.y;
  int ql = tid >> 2, d0 = (tid & 3) * 32;
  int tok = tokens[q0 + ql];
  const float4* src = (const float4*)(emb + (size_t)tok * HID + h * DH + d0);
  bf16x8 ob[4];
  #pragma unroll
  for (int i = 0; i < 8; i++) {
    float4 f = src[i];
    ob[i >> 1][(i & 1) * 4 + 0] = (bf16_t)f.x;
    ob[i >> 1][(i & 1) * 4 + 1] = (bf16_t)f.y;
    ob[i >> 1][(i & 1) * 4 + 2] = (bf16_t)f.z;
    ob[i >> 1][(i & 1) * 4 + 3] = (bf16_t)f.w;
  }
  store_h_hT(ob, tile, q0, h, ql, d0, tid, hb, hbT);
  // landmark rows -> hbL / hbLT
  unsigned long long lm = lmask[q0 >> 6];
  while (lm) {
    int r = __builtin_ctzll(lm);
    lm &= lm - 1;
    int li = lq[q0 + r];
    if (li >= 0 && tid < 128) {
      bf16_t vv = tile[r * 136 + tid];
      hbL[(size_t)li * HID + h * DH + tid] = vv;
      hbLT[((size_t)(h * DH + tid)) * LCAP + li] = vv;
    }
  }
}

// ---------------- fused attention layer: 64-q stripe, 2 waves, near+landmark tiles ----------------
__global__ __launch_bounds__(128, 2) void attn5(const bf16_t* __restrict__ hb,
                                                const bf16_t* __restrict__ hbT,
                                                const bf16_t* __restrict__ hbL,
                                                const bf16_t* __restrict__ hbLT,
                                                const unsigned* __restrict__ cmask,
                                                const int4* __restrict__ mi,
                                                const int2* __restrict__ smeta,
                                                const int* __restrict__ lq,
                                                const unsigned long long* __restrict__ lmask,
                                                bf16_t* __restrict__ ob,
                                                bf16_t* __restrict__ obT,
                                                bf16_t* __restrict__ obL,
                                                bf16_t* __restrict__ obLT,
                                                int writeT) {
  __shared__ __align__(16) char lds_raw[65536];

  int h = blockIdx.x, st = blockIdx.y;
  int2 sm = smeta[st];
  int nsT = sm.x, lcount = sm.y;
  int nNear = st + 1 - nsT;
  int nLT = (lcount + 63) >> 6;
  int nIter = nNear + nLT;

  int tid = threadIdx.x, w = tid >> 6, l = tid & 63, l31 = l & 31, hi = l >> 5;
  int q0 = 64 * st, q = q0 + 32 * w + l31;
  int npq = mi[q].x & 1;

  bf16x8 qf[8];
  {
    const bf16_t* hq = hb + (size_t)q * HID + h * DH;
    #pragma unroll
    for (int ks = 0; ks < 8; ks++) qf[ks] = *(const bf16x8*)(hq + ks * 16 + hi * 8);
  }

  f32x16 acc[4];
  #pragma unroll
  for (int i = 0; i < 4; i++)
    #pragma unroll
    for (int r = 0; r < 16; r++) acc[i][r] = 0.f;
  float m = -1e30f, lsum = 0.f;
  int swz = l31 & 7;

  auto STAGE = [&](int i, int b) {
    const bf16_t* Kbase; const bf16_t* Vbase; size_t Vstr;
    if (i < nNear) {
      int kv0 = (nsT + i) * 64;
      Kbase = hb + (size_t)kv0 * HID + h * DH;
      Vbase = hbT + (size_t)(h * DH) * S + kv0; Vstr = S;
    } else {
      int j0 = (i - nNear) * 64;
      Kbase = hbL + (size_t)j0 * HID + h * DH;
      Vbase = hbLT + (size_t)(h * DH) * LCAP + j0; Vstr = LCAP;
    }
    bf16_t* Kb = (bf16_t*)(lds_raw + b * 16384);
    bf16_t* Vb = (bf16_t*)(lds_raw + 32768 + b * 16384);
    #pragma unroll
    for (int i2 = 0; i2 < 8; i2++) {
      int sg = w * 8 + i2;
      int rowK = sg * 4 + (l >> 4); int chK = (l & 15) ^ (rowK & 7);
      gl_lds16(Kbase + (size_t)rowK * HID + chK * 8, Kb + sg * 512);
      int rowV = sg * 8 + (l >> 3); int chV = (l & 7) ^ (rowV & 7);
      gl_lds16(Vbase + (size_t)rowV * Vstr + chV * 8, Vb + sg * 512);
    }
  };

  auto getmask = [&](int i, unsigned& w0, unsigned& w1) {
    if (i < nNear) {
      int tt = nsT + i;
      w0 = cmask[(size_t)(2 * tt) * S + q];
      w1 = cmask[(size_t)(2 * tt + 1) * S + q];
    } else {
      int rem = lcount - (i - nNear) * 64;
      w0 = (rem >= 32) ? 0xffffffffu : ((rem <= 0) ? 0u : ((1u << rem) - 1u));
      int r2 = rem - 32;
      w1 = (r2 >= 32) ? 0xffffffffu : ((r2 <= 0) ? 0u : ((1u << r2) - 1u));
      if (!npq) { w0 = 0u; w1 = 0u; }
    }
  };

  // prologue
  STAGE(0, 0);
  asm volatile("s_waitcnt vmcnt(0)" ::: "memory");
  __builtin_amdgcn_s_barrier();
  __builtin_amdgcn_sched_barrier(0);

  for (int i = 0; i < nIter; i++) {
    int b = i & 1;
    if (i + 1 < nIter) STAGE(i + 1, b ^ 1);
    unsigned w0, w1;
    getmask(i, w0, w1);

    const bf16_t* Kb = (const bf16_t*)(lds_raw + b * 16384);
    const bf16_t* Vb = (const bf16_t*)(lds_raw + 32768 + b * 16384);
    f32x16 s0, s1;
    #pragma unroll
    for (int r = 0; r < 16; r++) { s0[r] = 0.f; s1[r] = 0.f; }
    const bf16_t* k0p = Kb + l31 * 128;
    const bf16_t* k1p = Kb + (32 + l31) * 128;
    #pragma unroll
    for (int ks = 0; ks < 8; ks++) {
      int ch = ((2 * ks + hi) ^ swz) * 8;
      bf16x8 kf0 = *(const bf16x8*)(k0p + ch);
      bf16x8 kf1 = *(const bf16x8*)(k1p + ch);
      s0 = MFMA32(kf0, qf[ks], s0, 0, 0, 0);
      s1 = MFMA32(kf1, qf[ks], s1, 0, 0, 0);
    }

    float sv0[16], sv1[16];
    float mx = NEGS;
    #pragma unroll
    for (int r = 0; r < 16; r++) {
      int bit = (r & 3) + 8 * (r >> 2) + 4 * hi;
      sv0[r] = ((w0 >> bit) & 1u) ? s0[r] : NEGS;
      sv1[r] = ((w1 >> bit) & 1u) ? s1[r] : NEGS;
      mx = fmaxf(mx, fmaxf(sv0[r], sv1[r]));
    }
    mx = fmaxf(mx, __shfl_xor(mx, 32, 64));
    if (__any(mx > m + RTHR)) {
      float mn = fmaxf(m, mx);
      float al = exp2f((m - mn) * K2EXP);
      m = mn; lsum *= al;
      #pragma unroll
      for (int r = 0; r < 16; r++) {
        float alr = __shfl(al, (r & 3) + 8 * (r >> 2) + 4 * hi, 64);
        #pragma unroll
        for (int d = 0; d < 4; d++) acc[d][r] *= alr;
      }
    }
    float mk = m * K2EXP;
    float p0[16], p1[16], ps = 0.f;
    #pragma unroll
    for (int r = 0; r < 16; r++) {
      p0[r] = exp2f(__builtin_fmaf(sv0[r], K2EXP, -mk));
      p1[r] = exp2f(__builtin_fmaf(sv1[r], K2EXP, -mk));
      ps += p0[r] + p1[r];
    }
    ps += __shfl_xor(ps, 32, 64);
    lsum += ps;

    bf16x8 pa[4];
    {
      unsigned a0 = cvtpk(p0[0], p0[1]),  a1 = cvtpk(p0[2], p0[3]);
      unsigned b0 = cvtpk(p0[4], p0[5]),  b1 = cvtpk(p0[6], p0[7]);
      unsigned a2 = cvtpk(p0[8], p0[9]),  a3 = cvtpk(p0[10], p0[11]);
      unsigned b2 = cvtpk(p0[12], p0[13]), b3 = cvtpk(p0[14], p0[15]);
      plswap(a0, b0); plswap(a1, b1); plswap(a2, b2); plswap(a3, b3);
      pa[0] = mk8(a0, a1, b0, b1);
      pa[1] = mk8(a2, a3, b2, b3);
      unsigned c0 = cvtpk(p1[0], p1[1]),  c1 = cvtpk(p1[2], p1[3]);
      unsigned d0 = cvtpk(p1[4], p1[5]),  d1 = cvtpk(p1[6], p1[7]);
      unsigned c2 = cvtpk(p1[8], p1[9]),  c3 = cvtpk(p1[10], p1[11]);
      unsigned d2 = cvtpk(p1[12], p1[13]), d3 = cvtpk(p1[14], p1[15]);
      plswap(c0, d0); plswap(c1, d1); plswap(c2, d2); plswap(c3, d3);
      pa[2] = mk8(c0, c1, d0, d1);
      pa[3] = mk8(c2, c3, d2, d3);
    }

    #pragma unroll
    for (int db = 0; db < 4; db++) {
      const bf16_t* vr = Vb + (32 * db + l31) * 64;
      #pragma unroll
      for (int ks = 0; ks < 4; ks++) {
        bf16x8 vf = *(const bf16x8*)(vr + ((2 * ks + hi) ^ swz) * 8);
        acc[db] = MFMA32(pa[ks], vf, acc[db], 0, 0, 0);
      }
    }

    asm volatile("s_waitcnt vmcnt(0)" ::: "memory");
    __builtin_amdgcn_s_barrier();
    __builtin_amdgcn_sched_barrier(0);
  }

  // epilogue: normalize, write hb / hbT / landmark copies (reuse LDS)
  bf16_t* tl = (bf16_t*)lds_raw;
  float inv = (lsum > 0.f) ? 1.f / lsum : 0.f;   // per-lane q-col = l31 (within wave half)
  #pragma unroll
  for (int r = 0; r < 16; r++) {
    int qr = (r & 3) + 8 * (r >> 2) + 4 * hi;
    float ivr = __shfl(inv, qr, 64);
    #pragma unroll
    for (int db = 0; db < 4; db++)
      tl[(32 * w + qr) * 132 + db * 32 + l31] = (bf16_t)(acc[db][r] * ivr);
  }
  __syncthreads();
  {
    int qr2 = tid >> 1;
    #pragma unroll
    for (int k = 0; k < 8; k++) {
      int ch = (tid & 1) * 8 + k;
      bf16x8 v = *(const bf16x8*)(tl + qr2 * 132 + ch * 8);
      *(bf16x8*)(ob + (size_t)(q0 + qr2) * HID + h * DH + ch * 8) = v;
    }
  }
  if (writeT) {
    int dd = tid;   // 0..127
    #pragma unroll
    for (int c = 0; c < 8; c++) {
      bf16x8 v;
      #pragma unroll
      for (int k = 0; k < 8; k++) v[k] = tl[(c * 8 + k) * 132 + dd];
      *(bf16x8*)(obT + (size_t)(h * DH + dd) * S + q0 + c * 8) = v;
    }
    unsigned long long lm = lmask[st];
    while (lm) {
      int r = __builtin_ctzll(lm);
      lm &= lm - 1;
      int li = lq[q0 + r];
      if (li >= 0) {
        bf16_t vv = tl[r * 132 + tid];
        obL[(size_t)li * HID + h * DH + tid] = vv;
        obLT[((size_t)(h * DH + tid)) * LCAP + li] = vv;
      }
    }
  }
}

// ---------------- lm head weight convert ----------------
__global__ __launch_bounds__(256) void wcvt(const float* __restrict__ w, bf16_t* __restrict__ wb) {
  int i = blockIdx.x * 256 + threadIdx.x;
  float4 f = ((const float4*)w)[i];
  bf16x4 v;
  v[0] = (bf16_t)f.x; v[1] = (bf16_t)f.y; v[2] = (bf16_t)f.z; v[3] = (bf16_t)f.w;
  *(bf16x4*)(wb + (size_t)i * 4) = v;
}

// ---------------- lm head + segment head fused ----------------
__global__ __launch_bounds__(256) void lmseg_head(const bf16_t* __restrict__ hb,
                                                  const bf16_t* __restrict__ wbf,
                                                  const float* __restrict__ bias,
                                                  const float* __restrict__ sw,
                                                  const float* __restrict__ sb,
                                                  float* __restrict__ out,
                                                  float* __restrict__ outseg) {
  __shared__ float red[4][16][130];
  int tid = threadIdx.x;
  int w = tid >> 6, l = tid & 63, l16 = l & 15, g = l >> 4;
  int t0 = blockIdx.x * 16;
  f32x4 acc[8];
  #pragma unroll
  for (int i = 0; i < 8; i++) acc[i] = (f32x4){0.f, 0.f, 0.f, 0.f};
  const bf16_t* arow = hb + (size_t)(t0 + l16) * HID + w * 512;
  for (int k0 = 0; k0 < 512; k0 += 32) {
    bf16x8 af = *(const bf16x8*)(arow + k0 + g * 8);
    #pragma unroll
    for (int vt = 0; vt < 8; vt++) {
      bf16x8 bf_ = *(const bf16x8*)(wbf + (size_t)(vt * 16 + l16) * HID + w * 512 + k0 + g * 8);
      acc[vt] = MFMA16(af, bf_, acc[vt], 0, 0, 0);
    }
  }
  #pragma unroll
  for (int vt = 0; vt < 8; vt++)
    #pragma unroll
    for (int r = 0; r < 4; r++)
      red[w][4 * g + r][vt * 16 + l16] = acc[vt][r];
  __syncthreads();
  int q = tid >> 4, vc = (tid & 15) * 8;
  #pragma unroll
  for (int j = 0; j < 8; j++) {
    float s = red[0][q][vc + j] + red[1][q][vc + j] + red[2][q][vc + j] + red[3][q][vc + j];
    out[(size_t)(t0 + q) * VOC + vc + j] = s + bias[vc + j];
  }
  // segment head: thread (q = tid>>4, c = tid&15) covers 128-elem chunk
  {
    int c = tid & 15;
    const bf16_t* hrow = hb + (size_t)(t0 + q) * HID + c * 128;
    float s0 = 0.f, s1 = 0.f;
    #pragma unroll
    for (int i = 0; i < 16; i++) {
      bf16x8 v = *(const bf16x8*)(hrow + i * 8);
      const float4* w0p = (const float4*)(sw + c * 128 + i * 8);
      const float4* w1p = (const float4*)(sw + HID + c * 128 + i * 8);
      float4 x0 = w0p[0], x1 = w0p[1], y0 = w1p[0], y1 = w1p[1];
      s0 += (float)v[0]*x0.x + (float)v[1]*x0.y + (float)v[2]*x0.z + (float)v[3]*x0.w
          + (float)v[4]*x1.x + (float)v[5]*x1.y + (float)v[6]*x1.z + (float)v[7]*x1.w;
      s1 += (float)v[0]*y0.x + (float)v[1]*y0.y + (float)v[2]*y0.z + (float)v[3]*y0.w
          + (float)v[4]*y1.x + (float)v[5]*y1.y + (float)v[6]*y1.z + (float)v[7]*y1.w;
    }
    #pragma unroll
    for (int off = 1; off < 16; off <<= 1) {
      s0 += __shfl_xor(s0, off, 64);
      s1 += __shfl_xor(s1, off, 64);
    }
    if (c == 0) {
      outseg[(size_t)(t0 + q) * 2] = s0 + sb[0];
      outseg[(size_t)(t0 + q) * 2 + 1] = s1 + sb[1];
    }
  }
}

extern "C" void kernel_launch(void* const* d_in, const int* in_sizes, int n_in,
                              void* d_out, int out_size, void* d_ws, size_t ws_size,
                              hipStream_t stream) {
  const int* tokens = (const int*)d_in[0];
  const unsigned char* seg = (const unsigned char*)d_in[1];
  const unsigned char* spc = (const unsigned char*)d_in[2];
  const float* emb_w = (const float*)d_in[3];
  const float* lm_w = (const float*)d_in[4];
  const float* lm_b = (const float*)d_in[5];
  const float* seg_w = (const float*)d_in[6];
  const float* seg_b = (const float*)d_in[7];

  char* ws = (char*)d_ws;
  int4* mi = (int4*)ws;                                              // 32KB @0
  unsigned* cmask = (unsigned*)(ws + (1u << 20));                    // 512KB @1MB
  int* lq = (int*)(ws + (1u << 20) + (512u << 10));                  // 8KB
  unsigned long long* lmask = (unsigned long long*)(ws + (1u << 20) + (520u << 10)); // 256B
  int2* smeta = (int2*)(ws + (1u << 20) + (524u << 10));             // 256B
  bf16_t* wbf = (bf16_t*)(ws + (2u << 20));                          // 512KB @2MB
  bf16_t* hbLA  = (bf16_t*)(ws + (3u << 20));                        // 512KB @3MB
  bf16_t* hbLTA = (bf16_t*)(ws + (3u << 20) + (512u << 10));         // 512KB
  bf16_t* hbLB  = (bf16_t*)(ws + (4u << 20));                        // 512KB @4MB
  bf16_t* hbLTB = (bf16_t*)(ws + (4u << 20) + (512u << 10));         // 512KB
  bf16_t* hbA  = (bf16_t*)(ws + (8u << 20));                         // 8MB @8MB
  bf16_t* hbTA = (bf16_t*)(ws + (16u << 20));                        // 8MB @16MB
  bf16_t* hbB  = (bf16_t*)(ws + (24u << 20));                        // 8MB @24MB
  bf16_t* hbTB = (bf16_t*)(ws + (32u << 20));                        // 8MB @32MB
  float* out = (float*)d_out;

  maskprep2<<<1, 256, 0, stream>>>(tokens, seg, spc, mi, lq, lmask, smeta);
  bitgen<<<dim3(64, 8), 256, 0, stream>>>(mi, cmask);
  embedT<<<dim3(S / 64, NH), 256, 0, stream>>>(tokens, emb_w, lq, lmask, hbA, hbTA, hbLA, hbLTA);

  bf16_t* cur = hbA;   bf16_t* curT = hbTA;
  bf16_t* nxt = hbB;   bf16_t* nxtT = hbTB;
  bf16_t* curL = hbLA; bf16_t* curLT = hbLTA;
  bf16_t* nxtL = hbLB; bf16_t* nxtLT = hbLTB;
  for (int L = 0; L < 4; L++) {
    attn5<<<dim3(NH, 32), 128, 0, stream>>>(cur, curT, curL, curLT, cmask, mi, smeta, lq, lmask,
                                            nxt, nxtT, nxtL, nxtLT, (L < 3) ? 1 : 0);
    bf16_t* t1 = cur; cur = nxt; nxt = t1;
    bf16_t* t2 = curT; curT = nxtT; nxtT = t2;
    bf16_t* t3 = curL; curL = nxtL; nxtL = t3;
    bf16_t* t4 = curLT; curLT = nxtLT; nxtLT = t4;
  }

  wcvt<<<(VOC * HID / 4) / 256, 256, 0, stream>>>(lm_w, wbf);
  lmseg_head<<<S / 16, 256, 0, stream>>>(cur, wbf, lm_b, seg_w, seg_b, out, out + (size_t)S * VOC);
}

// Round 9
// 140.856 us; speedup vs baseline: 2.9924x; 1.0207x over previous
//
#include <hip/hip_runtime.h>

#define S 2048
#define HID 2048
#define NH 16
#define DH 128
#define VOC 128
#define LCAP 128
#define K2EXP 0.12752551286084112f   // (1/sqrt(128)) * log2(e)
#define RTHR 62.0f                   // defer-max threshold in raw-score units
#define NEGS -3.0e38f

typedef __bf16 bf16_t;
typedef __attribute__((ext_vector_type(8))) __bf16 bf16x8;
typedef __attribute__((ext_vector_type(4))) __bf16 bf16x4;
typedef __attribute__((ext_vector_type(4))) float f32x4;
typedef __attribute__((ext_vector_type(16))) float f32x16;

typedef __attribute__((address_space(1))) unsigned int guint;
typedef __attribute__((address_space(3))) unsigned int luint;

#define MFMA16 __builtin_amdgcn_mfma_f32_16x16x32_bf16
#define MFMA32 __builtin_amdgcn_mfma_f32_32x32x16_bf16

__device__ __forceinline__ void gl_lds16(const void* g, void* l) {
  __builtin_amdgcn_global_load_lds((guint*)(unsigned long long)g,
                                   (luint*)(unsigned)(unsigned long long)l,
                                   16, 0, 0);
}

__device__ __forceinline__ unsigned cvtpk(float lo, float hi) {
  unsigned r;
  asm("v_cvt_pk_bf16_f32 %0, %1, %2" : "=v"(r) : "v"(lo), "v"(hi));
  return r;
}
__device__ __forceinline__ void plswap(unsigned& a, unsigned& b) {
  asm volatile("v_permlane32_swap_b32 %0, %1" : "+v"(a), "+v"(b));
}
__device__ __forceinline__ bf16x8 mk8(unsigned d0, unsigned d1, unsigned d2, unsigned d3) {
  union { unsigned u[4]; bf16x8 v; } x;
  x.u[0] = d0; x.u[1] = d1; x.u[2] = d2; x.u[3] = d3;
  return x.v;
}

// ---------------- mask precompute: intervals + starts + landmarks + stripe meta ----------------
__global__ __launch_bounds__(256) void maskprep2(const int* __restrict__ tokens,
                                                 const unsigned char* __restrict__ seg,
                                                 const unsigned char* __restrict__ spc,
                                                 int4* __restrict__ mi,
                                                 int* __restrict__ lq,
                                                 unsigned long long* __restrict__ lmask,
                                                 int2* __restrict__ smeta) {
  __shared__ int ssp[257], ssg[257], smw[257], sms[257], sfl[257];
  __shared__ int fpre[2048];
  __shared__ int ns16[16];
  __shared__ unsigned long long lmk[32];
  __shared__ int cdet[2];
  int t = threadIdx.x;
  if (t < 2) cdet[t] = 0;
  if (t < 32) lmk[t] = 0ull;
  __syncthreads();
  {
    int nz = ((t & 3) != 0 && seg[t]) ? 1 : 0;
    int fc = ((t & 3) == 3 && seg[t] == 0x3f) ? 1 : 0;
    if (nz) atomicAdd(&cdet[0], 1);
    if (fc) atomicAdd(&cdet[1], 1);
  }
  __syncthreads();
  int lay = (cdet[1] > 8) ? 2 : ((cdet[0] > 4) ? 1 : 0);
  auto getb = [&](const unsigned char* p, int i) -> int {
    if (lay == 1) return p[i] != 0;
    if (lay == 2) return ((const float*)p)[i] != 0.f;
    return ((const int*)p)[i] != 0;
  };
  int base = t * 8;
  int spv[8], sgv[8], npv[8], fv[8];
  int a = 0, b = 0, mw = 0, ms = 0, fs = 0;
  for (int j = 0; j < 8; j++) {
    int i = base + j;
    spv[j] = getb(spc, i);
    sgv[j] = 1 - getb(seg, i);
    npv[j] = (tokens[i] != 127) ? 1 : 0;
    fv[j] = spv[j] & sgv[j] & npv[j];
    a += spv[j]; b += sgv[j]; fs += fv[j];
    if (i >= 1 && spv[j]) mw = (i + 1 > mw) ? i + 1 : mw;
    if (i >= 1 && sgv[j]) ms = (i + 1 > ms) ? i + 1 : ms;
  }
  ssp[t + 1] = a; ssg[t + 1] = b; smw[t + 1] = mw; sms[t + 1] = ms; sfl[t + 1] = fs;
  if (t == 0) { ssp[0] = 0; ssg[0] = 0; smw[0] = 0; sms[0] = 0; sfl[0] = 0; }
  __syncthreads();
  for (int off = 1; off < 256; off <<= 1) {
    int v0 = 0, v1 = 0, v2 = 0, v3 = 0, v4 = 0;
    if (t + 1 > off) { v0 = ssp[t+1-off]; v1 = ssg[t+1-off]; v2 = smw[t+1-off]; v3 = sms[t+1-off]; v4 = sfl[t+1-off]; }
    __syncthreads();
    ssp[t + 1] += v0; ssg[t + 1] += v1;
    if (v2 > smw[t + 1]) smw[t + 1] = v2;
    if (v3 > sms[t + 1]) sms[t + 1] = v3;
    sfl[t + 1] += v4;
    __syncthreads();
  }
  // per-128-stripe near-start (exclusive prefix over [0, 128*st) at t = 16*st)
  if ((t & 15) == 0) {
    int ws = smw[t], ss = sms[t];
    ns16[t >> 4] = ws < ss ? ws : ss;
  }
  int esp = ssp[t], esg = ssg[t], ef = sfl[t];
  for (int j = 0; j < 8; j++) {
    int i = base + j;
    int wint = (i == 0) ? (1 + spv[j]) : (1 + esp);
    int sint = (i == 0) ? (1 + sgv[j]) : (1 + esg);
    mi[i] = make_int4(npv[j] | (spv[j] << 1) | (sgv[j] << 2), wint, sint, 0);
    fpre[i] = ef;
    int lqv = (fv[j] && ef < LCAP) ? ef : -1;
    lq[i] = lqv;
    if (lqv >= 0) atomicOr(&lmk[i >> 6], 1ull << (i & 63));
    esp += spv[j]; esg += sgv[j]; ef += fv[j];
  }
  __syncthreads();
  if (t < 32) lmask[t] = lmk[t];
  if (t < 16) {
    int nsTile = ns16[t] >> 6;
    int lc = fpre[nsTile * 64];          // fpre[0]==0
    if (lc > LCAP) lc = LCAP;
    smeta[t] = make_int2(nsTile, lc);
  }
}

// ---------------- full mask bit table: cmask[word][q], word=kv/32 ----------------
__global__ __launch_bounds__(256) void bitgen(const int4* __restrict__ mi,
                                              unsigned* __restrict__ cmask) {
  __shared__ int4 km[32];
  int w = blockIdx.x;
  int t = threadIdx.x;
  int q = blockIdx.y * 256 + t;
  if (t < 32) km[t] = mi[w * 32 + t];
  __syncthreads();
  int4 mq = mi[q];
  unsigned word = 0;
  #pragma unroll
  for (int j = 0; j < 32; j++) {
    int kv = w * 32 + j;
    int4 mk = km[j];
    bool v = ((mq.x & mk.x) & 1) &&
             ((mk.x & 2) || (mq.y == mk.y)) &&
             ((mk.x & 4) || (mq.z == mk.z)) &&
             (kv <= q);
    word |= (v ? 1u : 0u) << j;
  }
  cmask[(size_t)w * S + q] = word;
}

// ---------------- shared transpose-store helper (embed) ----------------
__device__ __forceinline__ void store_h_hT(bf16x8 ob[4], bf16_t* tile, int q0, int h,
                                           int ql, int d0, int tid,
                                           bf16_t* __restrict__ hb, bf16_t* __restrict__ hbT) {
  #pragma unroll
  for (int i = 0; i < 4; i++)
    *(bf16x8*)(hb + (size_t)(q0 + ql) * HID + h * DH + d0 + i * 8) = ob[i];
  #pragma unroll
  for (int i = 0; i < 4; i++)
    #pragma unroll
    for (int j = 0; j < 8; j++) tile[ql * 136 + d0 + i * 8 + j] = ob[i][j];
  __syncthreads();
  int dT = tid >> 1, qh = (tid & 1) * 32;
  bf16x8 tb[4];
  #pragma unroll
  for (int i = 0; i < 4; i++)
    #pragma unroll
    for (int j = 0; j < 8; j++) tb[i][j] = tile[(qh + i * 8 + j) * 136 + dT];
  #pragma unroll
  for (int i = 0; i < 4; i++)
    *(bf16x8*)(hbT + (size_t)(h * DH + dT) * S + q0 + qh + i * 8) = tb[i];
}

// ---------------- embedding gather -> bf16 h, h^T, and landmark copies ----------------
__global__ __launch_bounds__(256) void embedT(const int* __restrict__ tokens,
                                              const float* __restrict__ emb,
                                              const int* __restrict__ lq,
                                              const unsigned long long* __restrict__ lmask,
                                              bf16_t* __restrict__ hb, bf16_t* __restrict__ hbT,
                                              bf16_t* __restrict__ hbL, bf16_t* __restrict__ hbLT) {
  __shared__ bf16_t tile[64 * 136];
  int tid = threadIdx.x;
  int q0 = blockIdx.x * 64, h = blockIdx.y;
  int ql = tid >> 2, d0 = (tid & 3) * 32;
  int tok = tokens[q0 + ql];
  const float4* src = (const float4*)(emb + (size_t)tok * HID + h * DH + d0);
  bf16x8 ob[4];
  #pragma unroll
  for (int i = 0; i < 8; i++) {
    float4 f = src[i];
    ob[i >> 1][(i & 1) * 4 + 0] = (bf16_t)f.x;
    ob[i >> 1][(i & 1) * 4 + 1] = (bf16_t)f.y;
    ob[i >> 1][(i & 1) * 4 + 2] = (bf16_t)f.z;
    ob[i >> 1][(i & 1) * 4 + 3] = (bf16_t)f.w;
  }
  store_h_hT(ob, tile, q0, h, ql, d0, tid, hb, hbT);
  unsigned long long lm = lmask[q0 >> 6];
  while (lm) {
    int r = __builtin_ctzll(lm);
    lm &= lm - 1;
    int li = lq[q0 + r];
    if (li >= 0 && tid < 128) {
      bf16_t vv = tile[r * 136 + tid];
      hbL[(size_t)li * HID + h * DH + tid] = vv;
      hbLT[((size_t)(h * DH + tid)) * LCAP + li] = vv;
    }
  }
}

// ---------------- fused attention layer: 128-q stripe, 4 waves, near+landmark tiles ----------------
__global__ __launch_bounds__(256, 2) void attn6(const bf16_t* __restrict__ hb,
                                                const bf16_t* __restrict__ hbT,
                                                const bf16_t* __restrict__ hbL,
                                                const bf16_t* __restrict__ hbLT,
                                                const unsigned* __restrict__ cmask,
                                                const int4* __restrict__ mi,
                                                const int2* __restrict__ smeta,
                                                const int* __restrict__ lq,
                                                const unsigned long long* __restrict__ lmask,
                                                bf16_t* __restrict__ ob,
                                                bf16_t* __restrict__ obT,
                                                bf16_t* __restrict__ obL,
                                                bf16_t* __restrict__ obLT,
                                                int writeT) {
  __shared__ __align__(16) char lds_raw[65536];

  int h = blockIdx.x, st = blockIdx.y;
  int2 sm = smeta[st];
  int nsT = sm.x, lcount = sm.y;
  int nNear = 2 * st + 2 - nsT;
  int nLT = (lcount + 63) >> 6;
  int nIter = nNear + nLT;

  int tid = threadIdx.x, w = tid >> 6, l = tid & 63, l31 = l & 31, hi = l >> 5;
  int q0 = 128 * st, q = q0 + 32 * w + l31;
  int npq = mi[q].x & 1;

  bf16x8 qf[8];
  {
    const bf16_t* hq = hb + (size_t)q * HID + h * DH;
    #pragma unroll
    for (int ks = 0; ks < 8; ks++) qf[ks] = *(const bf16x8*)(hq + ks * 16 + hi * 8);
  }

  f32x16 acc[4];
  #pragma unroll
  for (int i = 0; i < 4; i++)
    #pragma unroll
    for (int r = 0; r < 16; r++) acc[i][r] = 0.f;
  float m = -1e30f, lsum = 0.f;
  int swz = l31 & 7;

  auto STAGE = [&](int i, int b) {
    const bf16_t* Kbase; const bf16_t* Vbase; size_t Vstr;
    if (i < nNear) {
      int kv0 = (nsT + i) * 64;
      Kbase = hb + (size_t)kv0 * HID + h * DH;
      Vbase = hbT + (size_t)(h * DH) * S + kv0; Vstr = S;
    } else {
      int j0 = (i - nNear) * 64;
      Kbase = hbL + (size_t)j0 * HID + h * DH;
      Vbase = hbLT + (size_t)(h * DH) * LCAP + j0; Vstr = LCAP;
    }
    bf16_t* Kb = (bf16_t*)(lds_raw + b * 16384);
    bf16_t* Vb = (bf16_t*)(lds_raw + 32768 + b * 16384);
    #pragma unroll
    for (int i2 = 0; i2 < 4; i2++) {
      int sg = w * 4 + i2;
      int rowK = sg * 4 + (l >> 4); int chK = (l & 15) ^ (rowK & 7);
      gl_lds16(Kbase + (size_t)rowK * HID + chK * 8, Kb + sg * 512);
      int rowV = sg * 8 + (l >> 3); int chV = (l & 7) ^ (rowV & 7);
      gl_lds16(Vbase + (size_t)rowV * Vstr + chV * 8, Vb + sg * 512);
    }
  };

  auto getmask = [&](int i, unsigned& w0, unsigned& w1) {
    if (i < nNear) {
      int tt = nsT + i;
      w0 = cmask[(size_t)(2 * tt) * S + q];
      w1 = cmask[(size_t)(2 * tt + 1) * S + q];
    } else {
      int rem = lcount - (i - nNear) * 64;
      w0 = (rem >= 32) ? 0xffffffffu : ((rem <= 0) ? 0u : ((1u << rem) - 1u));
      int r2 = rem - 32;
      w1 = (r2 >= 32) ? 0xffffffffu : ((r2 <= 0) ? 0u : ((1u << r2) - 1u));
      if (!npq) { w0 = 0u; w1 = 0u; }
    }
  };

  // prologue
  STAGE(0, 0);
  asm volatile("s_waitcnt vmcnt(0)" ::: "memory");
  __builtin_amdgcn_s_barrier();

  for (int i = 0; i < nIter; i++) {
    int b = i & 1;
    if (i + 1 < nIter) STAGE(i + 1, b ^ 1);
    unsigned w0, w1;
    getmask(i, w0, w1);

    const bf16_t* Kb = (const bf16_t*)(lds_raw + b * 16384);
    const bf16_t* Vb = (const bf16_t*)(lds_raw + 32768 + b * 16384);
    f32x16 s0, s1;
    #pragma unroll
    for (int r = 0; r < 16; r++) { s0[r] = 0.f; s1[r] = 0.f; }
    const bf16_t* k0p = Kb + l31 * 128;
    const bf16_t* k1p = Kb + (32 + l31) * 128;
    __builtin_amdgcn_s_setprio(1);
    #pragma unroll
    for (int ks = 0; ks < 8; ks++) {
      int ch = ((2 * ks + hi) ^ swz) * 8;
      bf16x8 kf0 = *(const bf16x8*)(k0p + ch);
      bf16x8 kf1 = *(const bf16x8*)(k1p + ch);
      s0 = MFMA32(kf0, qf[ks], s0, 0, 0, 0);
      s1 = MFMA32(kf1, qf[ks], s1, 0, 0, 0);
    }
    __builtin_amdgcn_s_setprio(0);

    float sv0[16], sv1[16];
    float mx = NEGS;
    #pragma unroll
    for (int r = 0; r < 16; r++) {
      int bit = (r & 3) + 8 * (r >> 2) + 4 * hi;
      sv0[r] = ((w0 >> bit) & 1u) ? s0[r] : NEGS;
      sv1[r] = ((w1 >> bit) & 1u) ? s1[r] : NEGS;
      mx = fmaxf(mx, fmaxf(sv0[r], sv1[r]));
    }
    mx = fmaxf(mx, __shfl_xor(mx, 32, 64));
    if (__any(mx > m + RTHR)) {
      float mn = fmaxf(m, mx);
      float al = exp2f((m - mn) * K2EXP);
      m = mn; lsum *= al;
      #pragma unroll
      for (int r = 0; r < 16; r++) {
        float alr = __shfl(al, (r & 3) + 8 * (r >> 2) + 4 * hi, 64);
        #pragma unroll
        for (int d = 0; d < 4; d++) acc[d][r] *= alr;
      }
    }
    float mk = m * K2EXP;
    float p0[16], p1[16], ps = 0.f;
    #pragma unroll
    for (int r = 0; r < 16; r++) {
      p0[r] = exp2f(__builtin_fmaf(sv0[r], K2EXP, -mk));
      p1[r] = exp2f(__builtin_fmaf(sv1[r], K2EXP, -mk));
      ps += p0[r] + p1[r];
    }
    ps += __shfl_xor(ps, 32, 64);
    lsum += ps;

    bf16x8 pa[4];
    {
      unsigned a0 = cvtpk(p0[0], p0[1]),  a1 = cvtpk(p0[2], p0[3]);
      unsigned b0 = cvtpk(p0[4], p0[5]),  b1 = cvtpk(p0[6], p0[7]);
      unsigned a2 = cvtpk(p0[8], p0[9]),  a3 = cvtpk(p0[10], p0[11]);
      unsigned b2 = cvtpk(p0[12], p0[13]), b3 = cvtpk(p0[14], p0[15]);
      plswap(a0, b0); plswap(a1, b1); plswap(a2, b2); plswap(a3, b3);
      pa[0] = mk8(a0, a1, b0, b1);
      pa[1] = mk8(a2, a3, b2, b3);
      unsigned c0 = cvtpk(p1[0], p1[1]),  c1 = cvtpk(p1[2], p1[3]);
      unsigned d0 = cvtpk(p1[4], p1[5]),  d1 = cvtpk(p1[6], p1[7]);
      unsigned c2 = cvtpk(p1[8], p1[9]),  c3 = cvtpk(p1[10], p1[11]);
      unsigned d2 = cvtpk(p1[12], p1[13]), d3 = cvtpk(p1[14], p1[15]);
      plswap(c0, d0); plswap(c1, d1); plswap(c2, d2); plswap(c3, d3);
      pa[2] = mk8(c0, c1, d0, d1);
      pa[3] = mk8(c2, c3, d2, d3);
    }

    __builtin_amdgcn_s_setprio(1);
    #pragma unroll
    for (int db = 0; db < 4; db++) {
      const bf16_t* vr = Vb + (32 * db + l31) * 64;
      #pragma unroll
      for (int ks = 0; ks < 4; ks++) {
        bf16x8 vf = *(const bf16x8*)(vr + ((2 * ks + hi) ^ swz) * 8);
        acc[db] = MFMA32(pa[ks], vf, acc[db], 0, 0, 0);
      }
    }
    __builtin_amdgcn_s_setprio(0);

    asm volatile("s_waitcnt vmcnt(0)" ::: "memory");
    __builtin_amdgcn_s_barrier();
  }

  // epilogue: normalize, write hb / hbT / landmark copies (reuse LDS)
  bf16_t* tl = (bf16_t*)lds_raw;
  float inv = (lsum > 0.f) ? 1.f / lsum : 0.f;
  #pragma unroll
  for (int r = 0; r < 16; r++) {
    int qr = (r & 3) + 8 * (r >> 2) + 4 * hi;
    float ivr = __shfl(inv, qr, 64);
    #pragma unroll
    for (int db = 0; db < 4; db++)
      tl[(32 * w + qr) * 132 + db * 32 + l31] = (bf16_t)(acc[db][r] * ivr);
  }
  __syncthreads();
  {
    int qr2 = tid >> 1;          // 0..127
    #pragma unroll
    for (int k = 0; k < 8; k++) {
      int ch = (tid & 1) * 8 + k;
      bf16x8 v = *(const bf16x8*)(tl + qr2 * 132 + ch * 8);
      *(bf16x8*)(ob + (size_t)(q0 + qr2) * HID + h * DH + ch * 8) = v;
    }
  }
  if (writeT) {
    int grp = tid >> 4, ln = tid & 15;   // 16 groups of 16 lanes
    #pragma unroll
    for (int k = 0; k < 8; k++) {
      int dd = grp * 8 + k;
      bf16x8 v;
      #pragma unroll
      for (int e = 0; e < 8; e++) v[e] = tl[(ln * 8 + e) * 132 + dd];
      *(bf16x8*)(obT + (size_t)(h * DH + dd) * S + q0 + ln * 8) = v;
    }
    #pragma unroll
    for (int wd = 0; wd < 2; wd++) {
      unsigned long long lm = lmask[2 * st + wd];
      while (lm) {
        int r = __builtin_ctzll(lm);
        lm &= lm - 1;
        int li = lq[q0 + wd * 64 + r];
        if (li >= 0 && tid < 128) {
          bf16_t vv = tl[(wd * 64 + r) * 132 + tid];
          obL[(size_t)li * HID + h * DH + tid] = vv;
          obLT[((size_t)(h * DH + tid)) * LCAP + li] = vv;
        }
      }
    }
  }
}

// ---------------- lm head weight convert ----------------
__global__ __launch_bounds__(256) void wcvt(const float* __restrict__ w, bf16_t* __restrict__ wb) {
  int i = blockIdx.x * 256 + threadIdx.x;
  float4 f = ((const float4*)w)[i];
  bf16x4 v;
  v[0] = (bf16_t)f.x; v[1] = (bf16_t)f.y; v[2] = (bf16_t)f.z; v[3] = (bf16_t)f.w;
  *(bf16x4*)(wb + (size_t)i * 4) = v;
}

// ---------------- lm head + segment head fused ----------------
__global__ __launch_bounds__(256) void lmseg_head(const bf16_t* __restrict__ hb,
                                                  const bf16_t* __restrict__ wbf,
                                                  const float* __restrict__ bias,
                                                  const float* __restrict__ sw,
                                                  const float* __restrict__ sb,
                                                  float* __restrict__ out,
                                                  float* __restrict__ outseg) {
  __shared__ float red[4][16][130];
  int tid = threadIdx.x;
  int w = tid >> 6, l = tid & 63, l16 = l & 15, g = l >> 4;
  int t0 = blockIdx.x * 16;
  f32x4 acc[8];
  #pragma unroll
  for (int i = 0; i < 8; i++) acc[i] = (f32x4){0.f, 0.f, 0.f, 0.f};
  const bf16_t* arow = hb + (size_t)(t0 + l16) * HID + w * 512;
  for (int k0 = 0; k0 < 512; k0 += 32) {
    bf16x8 af = *(const bf16x8*)(arow + k0 + g * 8);
    #pragma unroll
    for (int vt = 0; vt < 8; vt++) {
      bf16x8 bf_ = *(const bf16x8*)(wbf + (size_t)(vt * 16 + l16) * HID + w * 512 + k0 + g * 8);
      acc[vt] = MFMA16(af, bf_, acc[vt], 0, 0, 0);
    }
  }
  #pragma unroll
  for (int vt = 0; vt < 8; vt++)
    #pragma unroll
    for (int r = 0; r < 4; r++)
      red[w][4 * g + r][vt * 16 + l16] = acc[vt][r];
  __syncthreads();
  int q = tid >> 4, vc = (tid & 15) * 8;
  #pragma unroll
  for (int j = 0; j < 8; j++) {
    float s = red[0][q][vc + j] + red[1][q][vc + j] + red[2][q][vc + j] + red[3][q][vc + j];
    out[(size_t)(t0 + q) * VOC + vc + j] = s + bias[vc + j];
  }
  {
    int c = tid & 15;
    const bf16_t* hrow = hb + (size_t)(t0 + q) * HID + c * 128;
    float s0 = 0.f, s1 = 0.f;
    #pragma unroll
    for (int i = 0; i < 16; i++) {
      bf16x8 v = *(const bf16x8*)(hrow + i * 8);
      const float4* w0p = (const float4*)(sw + c * 128 + i * 8);
      const float4* w1p = (const float4*)(sw + HID + c * 128 + i * 8);
      float4 x0 = w0p[0], x1 = w0p[1], y0 = w1p[0], y1 = w1p[1];
      s0 += (float)v[0]*x0.x + (float)v[1]*x0.y + (float)v[2]*x0.z + (float)v[3]*x0.w
          + (float)v[4]*x1.x + (float)v[5]*x1.y + (float)v[6]*x1.z + (float)v[7]*x1.w;
      s1 += (float)v[0]*y0.x + (float)v[1]*y0.y + (float)v[2]*y0.z + (float)v[3]*y0.w
          + (float)v[4]*y1.x + (float)v[5]*y1.y + (float)v[6]*y1.z + (float)v[7]*y1.w;
    }
    #pragma unroll
    for (int off = 1; off < 16; off <<= 1) {
      s0 += __shfl_xor(s0, off, 64);
      s1 += __shfl_xor(s1, off, 64);
    }
    if (c == 0) {
      outseg[(size_t)(t0 + q) * 2] = s0 + sb[0];
      outseg[(size_t)(t0 + q) * 2 + 1] = s1 + sb[1];
    }
  }
}

extern "C" void kernel_launch(void* const* d_in, const int* in_sizes, int n_in,
                              void* d_out, int out_size, void* d_ws, size_t ws_size,
                              hipStream_t stream) {
  const int* tokens = (const int*)d_in[0];
  const unsigned char* seg = (const unsigned char*)d_in[1];
  const unsigned char* spc = (const unsigned char*)d_in[2];
  const float* emb_w = (const float*)d_in[3];
  const float* lm_w = (const float*)d_in[4];
  const float* lm_b = (const float*)d_in[5];
  const float* seg_w = (const float*)d_in[6];
  const float* seg_b = (const float*)d_in[7];

  char* ws = (char*)d_ws;
  int4* mi = (int4*)ws;                                              // 32KB @0
  unsigned* cmask = (unsigned*)(ws + (1u << 20));                    // 512KB @1MB
  int* lq = (int*)(ws + (1u << 20) + (512u << 10));                  // 8KB
  unsigned long long* lmask = (unsigned long long*)(ws + (1u << 20) + (520u << 10)); // 256B
  int2* smeta = (int2*)(ws + (1u << 20) + (524u << 10));             // 128B
  bf16_t* wbf = (bf16_t*)(ws + (2u << 20));                          // 512KB @2MB
  bf16_t* hbLA  = (bf16_t*)(ws + (3u << 20));                        // 512KB @3MB
  bf16_t* hbLTA = (bf16_t*)(ws + (3u << 20) + (512u << 10));         // 512KB
  bf16_t* hbLB  = (bf16_t*)(ws + (4u << 20));                        // 512KB @4MB
  bf16_t* hbLTB = (bf16_t*)(ws + (4u << 20) + (512u << 10));         // 512KB
  bf16_t* hbA  = (bf16_t*)(ws + (8u << 20));                         // 8MB @8MB
  bf16_t* hbTA = (bf16_t*)(ws + (16u << 20));                        // 8MB @16MB
  bf16_t* hbB  = (bf16_t*)(ws + (24u << 20));                        // 8MB @24MB
  bf16_t* hbTB = (bf16_t*)(ws + (32u << 20));                        // 8MB @32MB
  float* out = (float*)d_out;

  maskprep2<<<1, 256, 0, stream>>>(tokens, seg, spc, mi, lq, lmask, smeta);
  bitgen<<<dim3(64, 8), 256, 0, stream>>>(mi, cmask);
  embedT<<<dim3(S / 64, NH), 256, 0, stream>>>(tokens, emb_w, lq, lmask, hbA, hbTA, hbLA, hbLTA);

  bf16_t* cur = hbA;   bf16_t* curT = hbTA;
  bf16_t* nxt = hbB;   bf16_t* nxtT = hbTB;
  bf16_t* curL = hbLA; bf16_t* curLT = hbLTA;
  bf16_t* nxtL = hbLB; bf16_t* nxtLT = hbLTB;
  for (int L = 0; L < 4; L++) {
    attn6<<<dim3(NH, 16), 256, 0, stream>>>(cur, curT, curL, curLT, cmask, mi, smeta, lq, lmask,
                                            nxt, nxtT, nxtL, nxtLT, (L < 3) ? 1 : 0);
    bf16_t* t1 = cur; cur = nxt; nxt = t1;
    bf16_t* t2 = curT; curT = nxtT; nxtT = t2;
    bf16_t* t3 = curL; curL = nxtL; nxtL = t3;
    bf16_t* t4 = curLT; curLT = nxtLT; nxtLT = t4;
  }

  wcvt<<<(VOC * HID / 4) / 256, 256, 0, stream>>>(lm_w, wbf);
  lmseg_head<<<S / 16, 256, 0, stream>>>(cur, wbf, lm_b, seg_w, seg_b, out, out + (size_t)S * VOC);
}